// Round 4
// baseline (376.107 us; speedup 1.0000x reference)
//
#include <hip/hip_runtime.h>
#include <math.h>

#define V_WORDS 20000
#define MM 32
#define EE 128
#define HH 4
#define DHH 32
#define NN 8192
#define LL 64
#define CC 128

typedef short bf16x8 __attribute__((ext_vector_type(8)));
typedef float f32x4 __attribute__((ext_vector_type(4)));
typedef unsigned short u16;
typedef unsigned int u32;

__device__ __forceinline__ u16 f2bf(float x) {
    u32 u = __float_as_uint(x);
    u32 r = (u + 0x7FFFu + ((u >> 16) & 1u)) >> 16;
    return (u16)r;
}
__device__ __forceinline__ float bflo(u32 u) { return __uint_as_float(u << 16); }
__device__ __forceinline__ float bfhi(u32 u) { return __uint_as_float(u & 0xFFFF0000u); }

// bf16 pair dot-product: 1 VALU op on gfx950 (v_dot2_f32_bf16) vs 6 for the
// unpack+fma fallback. Guarded: falls back to exact-equivalent f32 math.
#if defined(__has_builtin)
#  if __has_builtin(__builtin_amdgcn_fdot2_f32_bf16)
#    define USE_BF16_DOT2 1
#  endif
#endif
#ifdef USE_BF16_DOT2
typedef __bf16 v2bf __attribute__((ext_vector_type(2)));
#endif

__device__ __forceinline__ float dot2bf(u32 a, u32 b, float c) {
#ifdef USE_BF16_DOT2
    return __builtin_amdgcn_fdot2_f32_bf16(
        __builtin_bit_cast(v2bf, a), __builtin_bit_cast(v2bf, b), c, false);
#else
    return c + bflo(a) * bflo(b) + bfhi(a) * bfhi(b);
#endif
}

// ---------------------------------------------------------------------------
// Conv-weight pack body (shared by standalone kernel + fused-into-proj path).
// ---------------------------------------------------------------------------
__device__ __forceinline__ void pack_body(int s, int t,
                                          const float* __restrict__ w3,
                                          const float* __restrict__ w4,
                                          const float* __restrict__ w5,
                                          u16* __restrict__ Bpack)
{
    const int lane = t & 63;
    const float* src;
    int K, sl;
    if (s < 12)      { src = w3; K = 3; sl = s; }
    else if (s < 28) { src = w4; K = 4; sl = s - 12; }
    else             { src = w5; K = 5; sl = s - 28; }
    const int j  = sl >> 2;
    const int e0 = (sl & 3) * 32;

    for (int nt = (t >> 6); nt < 8; nt += 4) {
        const int c = nt * 16 + (lane & 15);
        const int kb = (lane >> 4) * 8;
        u16 vals[8];
        #pragma unroll
        for (int i = 0; i < 8; ++i) {
            const int e = e0 + kb + i;
            vals[i] = f2bf(src[(c * EE + e) * K + j]);
        }
        u16* dst = Bpack + (((size_t)s * 8 + nt) * 64 + lane) * 8;
        *(bf16x8*)dst = *(const bf16x8*)vals;
    }
}

// ---------------------------------------------------------------------------
// Kernel 0 (fallback path only): standalone weight pack.
// ---------------------------------------------------------------------------
__global__ __launch_bounds__(256)
void pack_weights(const float* __restrict__ w3,
                  const float* __restrict__ w4,
                  const float* __restrict__ w5,
                  u16* __restrict__ Bpack)
{
    pack_body(blockIdx.x, threadIdx.x, w3, w4, w5, Bpack);
}

// ---------------------------------------------------------------------------
// Kernel A (fallback, ws too small): Kn/Vn projections (R15 path).
// ---------------------------------------------------------------------------
__global__ __launch_bounds__(256)
void kv_proj_kernel(const float* __restrict__ table,
                    const float* __restrict__ in_w,
                    const float* __restrict__ in_b,
                    u16* __restrict__ Kn16, u16* __restrict__ Vn16)
{
    const int n0 = blockIdx.x * 8;
    const int t = threadIdx.x;
    __shared__ float tbl[8][EE];
    {
        const int r = t >> 5, q4 = (t & 31) * 4;
        *(float4*)&tbl[r][q4] = *(const float4*)&table[(size_t)(n0 + r) * EE + q4];
    }
    __syncthreads();

    const int sel = t >> 7;
    const int i = t & 127;
    const float* w = in_w + (size_t)(sel + 1) * EE * EE + (size_t)i * EE;
    const float bias = in_b[(sel + 1) * EE + i];

    float acc[8];
    #pragma unroll
    for (int r = 0; r < 8; ++r) acc[r] = bias;
    for (int k = 0; k < EE; k += 4) {
        const float4 wv = *(const float4*)&w[k];
        #pragma unroll
        for (int r = 0; r < 8; ++r) {
            acc[r] += tbl[r][k]     * wv.x + tbl[r][k + 1] * wv.y
                    + tbl[r][k + 2] * wv.z + tbl[r][k + 3] * wv.w;
        }
    }
    u16* dst = sel ? Vn16 : Kn16;
    #pragma unroll
    for (int r = 0; r < 8; ++r) dst[(size_t)(n0 + r) * EE + i] = f2bf(acc[r]);
}

// ---------------------------------------------------------------------------
// Kernel A'' (R23): Q/K/W projections over the 8192 distinct news rows,
// with pack_weights fused in as 48 extra blocks (kills one launch gap;
// Bpack is consumed only by news_kernel, which launches later).
// ---------------------------------------------------------------------------
__global__ __launch_bounds__(384)
void kvqw_proj_kernel(const float* __restrict__ table,
                      const float* __restrict__ in_w,
                      const float* __restrict__ in_b,
                      const float* __restrict__ out_w,
                      const float* __restrict__ out_b,
                      const float* __restrict__ w3,
                      const float* __restrict__ w4,
                      const float* __restrict__ w5,
                      u16* __restrict__ Qn16,
                      u16* __restrict__ Kn16,
                      u16* __restrict__ Wn16,
                      u16* __restrict__ Bpack)
{
    const int t = threadIdx.x;
    if (blockIdx.x >= NN / 8) {                  // fused weight-pack blocks
        if (t < 256) pack_body(blockIdx.x - NN / 8, t, w3, w4, w5, Bpack);
        return;
    }

    const int n0 = blockIdx.x * 8;
    __shared__ float tbl[8][EE];
    __shared__ float vsh[8][EE];
    if (t < 256) {
        const int r = t >> 5, q4 = (t & 31) * 4;
        *(float4*)&tbl[r][q4] = *(const float4*)&table[(size_t)(n0 + r) * EE + q4];
    }
    __syncthreads();

    const int sel = t >> 7;                 // 0 = Q, 1 = K, 2 = V
    const int i = t & 127;
    const float* w = in_w + (size_t)sel * EE * EE + (size_t)i * EE;
    const float bias = in_b[sel * EE + i];

    float acc[8];
    #pragma unroll
    for (int r = 0; r < 8; ++r) acc[r] = bias;
    for (int k = 0; k < EE; k += 4) {
        const float4 wv = *(const float4*)&w[k];
        #pragma unroll
        for (int r = 0; r < 8; ++r) {
            acc[r] += tbl[r][k]     * wv.x + tbl[r][k + 1] * wv.y
                    + tbl[r][k + 2] * wv.z + tbl[r][k + 3] * wv.w;
        }
    }
    if (sel == 0) {
        #pragma unroll
        for (int r = 0; r < 8; ++r) Qn16[(size_t)(n0 + r) * EE + i] = f2bf(acc[r]);
    } else if (sel == 1) {
        #pragma unroll
        for (int r = 0; r < 8; ++r) Kn16[(size_t)(n0 + r) * EE + i] = f2bf(acc[r]);
    } else {
        #pragma unroll
        for (int r = 0; r < 8; ++r) vsh[r][i] = acc[r];   // keep V fp32 for phase 2
    }
    __syncthreads();

    // Phase 2: Wn[r][i] = vsh[r] . out_w[i] + out_b[i]
    {
        const int g = t >> 7;
        const int r0 = g, r1 = g + 3, r2 = g + 6;       // r2 == 8 invalid for g==2
        const int r2c = (r2 < 8) ? r2 : 7;
        const float* wr = out_w + (size_t)i * EE;
        const float ob = out_b[i];
        float a0 = ob, a1 = ob, a2 = ob;
        #pragma unroll 4
        for (int k = 0; k < EE; k += 4) {
            const float4 wv = *(const float4*)&wr[k];
            a0 += vsh[r0][k]   * wv.x + vsh[r0][k+1] * wv.y
                + vsh[r0][k+2] * wv.z + vsh[r0][k+3] * wv.w;
            a1 += vsh[r1][k]   * wv.x + vsh[r1][k+1] * wv.y
                + vsh[r1][k+2] * wv.z + vsh[r1][k+3] * wv.w;
            a2 += vsh[r2c][k]   * wv.x + vsh[r2c][k+1] * wv.y
                + vsh[r2c][k+2] * wv.z + vsh[r2c][k+3] * wv.w;
        }
        Wn16[(size_t)(n0 + r0) * EE + i] = f2bf(a0);
        Wn16[(size_t)(n0 + r1) * EE + i] = f2bf(a1);
        if (r2 < 8) Wn16[(size_t)(n0 + r2) * EE + i] = f2bf(a2);
    }
}

// ---------------------------------------------------------------------------
// Kernel B (fallback): per-word attention, R15 path (unchanged).
// ---------------------------------------------------------------------------
#define WPB 8
__global__ __launch_bounds__(256, 3)
void word_attn_kernel(const int* __restrict__ word2news,
                      const int* __restrict__ word2news_len,
                      const float* __restrict__ table,
                      const float* __restrict__ in_w,
                      const float* __restrict__ in_b,
                      const float* __restrict__ out_w,
                      const float* __restrict__ out_b,
                      const u16* __restrict__ Kn16,
                      const u16* __restrict__ Vn16,
                      u16* __restrict__ we16)
{
    const int v0 = blockIdx.x * WPB;
    const int t = threadIdx.x;

    __shared__ int   rows[WPB][MM];
    __shared__ int   lenS[WPB];
    __shared__ float q[WPB][EE];
    __shared__ float qh[WPB][EE];
    __shared__ float attn[WPB][HH][MM];
    __shared__ float osh[WPB][EE];

    {
        const int w = t >> 5, m = t & 31;
        rows[w][m] = word2news[(size_t)(v0 + w) * MM + m];
        if (t < WPB) lenS[t] = word2news_len[v0 + t];
    }
    __syncthreads();

    {
        const int w = t >> 5, d0 = (t & 31) * 4;
        const int L = lenS[w];
        float4 a = {0.f, 0.f, 0.f, 0.f};
        #pragma unroll 4
        for (int m = 0; m < MM; ++m) {
            const float4 x = *(const float4*)&table[(size_t)rows[w][m] * EE + d0];
            if (m < L) { a.x += x.x; a.y += x.y; a.z += x.z; a.w += x.w; }
        }
        const float inv = (L > 0) ? 1.0f / (float)L : 0.0f;
        a.x *= inv; a.y *= inv; a.z *= inv; a.w *= inv;
        *(float4*)&q[w][d0] = a;
    }
    __syncthreads();

    {
        const int g = t >> 7, i = t & 127;
        const float* wr = in_w + (size_t)i * EE;
        float acc[4] = {0.f, 0.f, 0.f, 0.f};
        #pragma unroll 4
        for (int k = 0; k < EE; k += 4) {
            const float4 wv = *(const float4*)&wr[k];
            #pragma unroll
            for (int w4 = 0; w4 < 4; ++w4) {
                const float* qw = q[g * 4 + w4];
                acc[w4] += qw[k] * wv.x + qw[k + 1] * wv.y
                         + qw[k + 2] * wv.z + qw[k + 3] * wv.w;
            }
        }
        const float b = in_b[i];
        #pragma unroll
        for (int w4 = 0; w4 < 4; ++w4) qh[g * 4 + w4][i] = acc[w4] + b;
    }
    __syncthreads();

    {
        const int w = t >> 5, m = t & 31;
        const int L = lenS[w];
        float s[HH] = {-1e9f, -1e9f, -1e9f, -1e9f};
        if (m < L) {
            const uint4* kr = (const uint4*)(Kn16 + (size_t)rows[w][m] * EE);
            #pragma unroll 1
            for (int h = 0; h < HH; ++h) {
                float a = 0.f;
                #pragma unroll
                for (int k8 = 0; k8 < 4; ++k8) {
                    const uint4 u = kr[h * 4 + k8];
                    const float4 q0 = *(const float4*)&qh[w][h * 32 + k8 * 8];
                    const float4 q1 = *(const float4*)&qh[w][h * 32 + k8 * 8 + 4];
                    a += q0.x * bflo(u.x) + q0.y * bfhi(u.x)
                       + q0.z * bflo(u.y) + q0.w * bfhi(u.y)
                       + q1.x * bflo(u.z) + q1.y * bfhi(u.z)
                       + q1.z * bflo(u.w) + q1.w * bfhi(u.w);
                }
                s[h] = a * 0.17677669529663687f;
            }
        }
        #pragma unroll
        for (int h = 0; h < HH; ++h) {
            float mx = s[h];
            #pragma unroll
            for (int off = 16; off > 0; off >>= 1)
                mx = fmaxf(mx, __shfl_xor(mx, off, 32));
            const float ex = expf(s[h] - mx);
            float sum = ex;
            #pragma unroll
            for (int off = 16; off > 0; off >>= 1)
                sum += __shfl_xor(sum, off, 32);
            attn[w][h][m] = ex / sum;
        }
    }
    __syncthreads();

    {
        const int w = t >> 5, d0 = (t & 31) * 4;
        const int h = d0 >> 5;
        float4 a = {0.f, 0.f, 0.f, 0.f};
        #pragma unroll 4
        for (int m = 0; m < MM; ++m) {
            const float aw = attn[w][h][m];
            const u32* vr = (const u32*)(Vn16 + (size_t)rows[w][m] * EE + d0);
            const u32 u0 = vr[0], u1 = vr[1];
            a.x += aw * bflo(u0); a.y += aw * bfhi(u0);
            a.z += aw * bflo(u1); a.w += aw * bfhi(u1);
        }
        *(float4*)&osh[w][d0] = a;
    }
    __syncthreads();

    {
        const int g = t >> 7, i = t & 127;
        const float* wr = out_w + (size_t)i * EE;
        float acc[4] = {0.f, 0.f, 0.f, 0.f};
        #pragma unroll 4
        for (int k = 0; k < EE; k += 4) {
            const float4 wv = *(const float4*)&wr[k];
            #pragma unroll
            for (int w4 = 0; w4 < 4; ++w4) {
                const float* ow = osh[g * 4 + w4];
                acc[w4] += ow[k] * wv.x + ow[k + 1] * wv.y
                         + ow[k + 2] * wv.z + ow[k + 3] * wv.w;
            }
        }
        const float b = out_b[i];
        #pragma unroll
        for (int w4 = 0; w4 < 4; ++w4) {
            const int w = g * 4 + w4;
            we16[(size_t)(v0 + w) * EE + i] =
                (lenS[w] > 0) ? f2bf(acc[w4] + b) : (u16)0;
        }
    }
}

// ---------------------------------------------------------------------------
// Kernel B'' (R23): per-word attention, BARRIER-FREE. Every LDS slice
// (rows, qhp, attn) is produced and consumed by the SAME 32-lane group,
// i.e. within one 64-lane wave. CDNA DS ops execute in program order per
// wave, so the 3 __syncthreads() of R22 only added (a) wait-for-slowest-
// of-8-words imbalance (E[max8 L]=29 vs E[L]=15.5 per phase) and (b)
// vmcnt(0)/lgkmcnt(0) drains. Removed; sched_barrier(0) (zero-cost) pins
// compiler ordering of LDS write->read. lenS LDS broadcast replaced by a
// direct per-lane load. expf -> __expf (v_exp_f32, ~1ulp).
// ---------------------------------------------------------------------------
__global__ __launch_bounds__(256, 3)
void word_attn_wn(const int* __restrict__ word2news,
                  const int* __restrict__ word2news_len,
                  const u16* __restrict__ Qn16,
                  const u16* __restrict__ Kn16,
                  const u16* __restrict__ Wn16,
                  u16* __restrict__ we16)
{
    const int v0 = blockIdx.x * WPB;
    const int t = threadIdx.x;
    const int w = t >> 5, m = t & 31;

    __shared__ int   rows[WPB][MM];
    __shared__ __align__(16) u32 qhp[WPB][EE / 2];   // bf16-pair packed query
    __shared__ float attn[WPB][HH][MM];

    const int L = word2news_len[v0 + w];             // wave-uniform per group

    rows[w][m] = word2news[(size_t)(v0 + w) * MM + m];
    __builtin_amdgcn_sched_barrier(0);   // LDS write->read order (same wave)

    // qh = mean of gathered Qn rows (bias included; exact — weights sum to 1).
    // Loop to L only (uniform per 32-lane group); pack result as bf16 pairs.
    {
        const int d0 = m * 4;
        float4 a = {0.f, 0.f, 0.f, 0.f};
        #pragma unroll 4
        for (int mm = 0; mm < L; ++mm) {
            const uint2 u = *(const uint2*)(Qn16 + (size_t)rows[w][mm] * EE + d0);
            a.x += bflo(u.x); a.y += bfhi(u.x);
            a.z += bflo(u.y); a.w += bfhi(u.y);
        }
        const float inv = (L > 0) ? 1.0f / (float)L : 0.0f;
        a.x *= inv; a.y *= inv; a.z *= inv; a.w *= inv;
        qhp[w][(d0 >> 1) + 0] = (u32)f2bf(a.x) | ((u32)f2bf(a.y) << 16);
        qhp[w][(d0 >> 1) + 1] = (u32)f2bf(a.z) | ((u32)f2bf(a.w) << 16);
    }
    __builtin_amdgcn_sched_barrier(0);   // qhp write->read order (same wave)

    // scores (gather Kn rows) + softmax over m; head-PAIR at a time with the
    // pair's 8 uint4 (128B) prefetched before any dot -> 8 loads in flight.
    {
        float s[HH] = {-1e9f, -1e9f, -1e9f, -1e9f};
        if (m < L) {
            const uint4* kr = (const uint4*)(Kn16 + (size_t)rows[w][m] * EE);
            const u32* qp = qhp[w];
            #pragma unroll
            for (int hp = 0; hp < 2; ++hp) {
                uint4 kq[8];
                #pragma unroll
                for (int q8 = 0; q8 < 8; ++q8) kq[q8] = kr[hp * 8 + q8];
                #pragma unroll
                for (int hl = 0; hl < 2; ++hl) {
                    const int h = hp * 2 + hl;
                    float a = 0.f;
                    #pragma unroll
                    for (int k8 = 0; k8 < 4; ++k8) {
                        const uint4 u  = kq[hl * 4 + k8];
                        const uint4 qq = *(const uint4*)&qp[h * 16 + k8 * 4];
                        a = dot2bf(u.x, qq.x, a);
                        a = dot2bf(u.y, qq.y, a);
                        a = dot2bf(u.z, qq.z, a);
                        a = dot2bf(u.w, qq.w, a);
                    }
                    s[h] = a * 0.17677669529663687f;
                }
            }
        }
        #pragma unroll
        for (int h = 0; h < HH; ++h) {
            float mx = s[h];
            #pragma unroll
            for (int off = 16; off > 0; off >>= 1)
                mx = fmaxf(mx, __shfl_xor(mx, off, 32));
            const float ex = __expf(s[h] - mx);    // masked lanes underflow to 0
            float sum = ex;
            #pragma unroll
            for (int off = 16; off > 0; off >>= 1)
                sum += __shfl_xor(sum, off, 32);
            attn[w][h][m] = ex / sum;
        }
    }
    __builtin_amdgcn_sched_barrier(0);   // attn write->read order (same wave)

    // we = sum_{m<L} attn_m * Wn[rows[m]]  (out-proj + bias pre-folded into
    // Wn; attn==0 exactly for m>=L so the truncation is exact).
    {
        const int d0 = m * 4;
        const int h = d0 >> 5;
        float4 a = {0.f, 0.f, 0.f, 0.f};
        #pragma unroll 4
        for (int mm = 0; mm < L; ++mm) {
            const float aw = attn[w][h][mm];
            const uint2 u = *(const uint2*)(Wn16 + (size_t)rows[w][mm] * EE + d0);
            a.x += aw * bflo(u.x); a.y += aw * bfhi(u.x);
            a.z += aw * bflo(u.y); a.w += aw * bfhi(u.y);
        }
        u32 lo = 0u, hi = 0u;
        if (L > 0) {
            lo = (u32)f2bf(a.x) | ((u32)f2bf(a.y) << 16);
            hi = (u32)f2bf(a.z) | ((u32)f2bf(a.w) << 16);
        }
        u32* dst = (u32*)(we16 + (size_t)(v0 + w) * EE + d0);
        dst[0] = lo; dst[1] = hi;
    }
}

// ---------------------------------------------------------------------------
// Kernel 2: implicit-GEMM conv — R16/R18 MEASURED OPTIMUM, unchanged.
// (#pragma unroll 2; full unroll spills — R20 measured 14x regression.)
// ---------------------------------------------------------------------------
#define DSTRIDE 136              // u16 per doc row (16B-aligned, 68 words)
#define DOCSZ   (68 * DSTRIDE)   // u16 per doc (64 data rows + 4 zero rows)

template<int NSL, int SBASE, int NP>
__device__ __forceinline__ void conv_g2(const u16* __restrict__ lds,
                                        const u16* __restrict__ Bpack,
                                        const float* __restrict__ bk,
                                        int p, int nth, int l,
                                        float (&mxout)[4])
{
    f32x4 acc[4][4];
    #pragma unroll
    for (int mt = 0; mt < 4; ++mt)
        #pragma unroll
        for (int k = 0; k < 4; ++k)
            acc[mt][k] = (f32x4){0.f, 0.f, 0.f, 0.f};

    const int lm = l & 15;
    const int g  = l >> 4;
    const u16* bbase = Bpack + ((size_t)SBASE * 8 + nth * 4) * 512 + l * 8;
    const u16* abase = lds + (size_t)p * DOCSZ;

    #pragma unroll 2
    for (int s = 0; s < NSL; ++s) {
        const int j  = s >> 2;
        const int e0 = (s & 3) * 32;

        bf16x8 b[4];
        #pragma unroll
        for (int k = 0; k < 4; ++k)
            b[k] = *(const bf16x8*)(bbase + s * 4096 + k * 512);

        const u16* arow = abase + (lm + j) * DSTRIDE + e0 + g * 8;
        bf16x8 a[4];
        #pragma unroll
        for (int mt = 0; mt < 4; ++mt)
            a[mt] = *(const bf16x8*)(arow + mt * (16 * DSTRIDE));

        #pragma unroll
        for (int mt = 0; mt < 4; ++mt)
            #pragma unroll
            for (int k = 0; k < 4; ++k)
                acc[mt][k] = __builtin_amdgcn_mfma_f32_16x16x32_bf16(a[mt], b[k], acc[mt][k], 0, 0, 0);
    }

    #pragma unroll
    for (int k = 0; k < 4; ++k) {
        const int c = nth * 64 + k * 16 + lm;
        const float bias = bk[c];
        float mx = 0.0f;                     // relu output >= 0
        #pragma unroll
        for (int mt = 0; mt < 4; ++mt) {
            #pragma unroll
            for (int r = 0; r < 4; ++r) {
                const int pos = 16 * mt + g * 4 + r;
                const float y = fmaxf(acc[mt][k][r] + bias, 0.0f);
                if (pos < NP) mx = fmaxf(mx, y);
            }
        }
        mx = fmaxf(mx, __shfl_xor(mx, 16));
        mx = fmaxf(mx, __shfl_xor(mx, 32));
        mxout[k] = mx;
    }
}

__global__ __launch_bounds__(512, 4)
void news_kernel(const int* __restrict__ news_words,
                 const u16* __restrict__ we16,
                 const u16* __restrict__ Bpack,
                 const float* __restrict__ b3,
                 const float* __restrict__ b4,
                 const float* __restrict__ b5,
                 const float* __restrict__ fcw, const float* __restrict__ fcb,
                 float* __restrict__ out)
{
    const int n0 = blockIdx.x * 4;
    const int t = threadIdx.x;
    const int w = t >> 6, l = t & 63;
    const int p = w >> 1, nth = w & 1;

    __shared__ u16 lds[4 * DOCSZ];           // 73,984 B; feats alias after convs
    __shared__ int rows[4 * LL];

    if (t < 4 * LL) rows[t] = news_words[(size_t)n0 * LL + t];
    __syncthreads();

    {
        const uint4* weU = (const uint4*)we16;     // 16 uint4 per doc row
        uint4* ldsU = (uint4*)lds;                 // doc stride 1156 uint4
        for (int idx = t; idx < 4096; idx += 512) {
            const int d = idx >> 10, rem = idx & 1023;
            const int row = rem >> 4, c4 = rem & 15;
            ldsU[d * 1156 + row * 17 + c4] = weU[(size_t)rows[d * 64 + row] * 16 + c4];
        }
        if (t < 256) {                             // 4 docs x 4 pad rows x 16
            const int d = t >> 6, rem = t & 63;
            const int row = 64 + (rem >> 4), c4 = rem & 15;
            ldsU[d * 1156 + row * 17 + c4] = (uint4){0u, 0u, 0u, 0u};
        }
    }
    __syncthreads();

    float m3[4], m4[4], m5[4];
    conv_g2<12,  0, 62>(lds, Bpack, b3, p, nth, l, m3);
    conv_g2<16, 12, 61>(lds, Bpack, b4, p, nth, l, m4);
    conv_g2<20, 28, 60>(lds, Bpack, b5, p, nth, l, m5);
    __syncthreads();                          // docs dead beyond this point

    float* feats = (float*)lds;               // [4][384] aliases doc buffer
    if ((l >> 4) == 0) {
        const int lm = l & 15;
        #pragma unroll
        for (int k = 0; k < 4; ++k) {
            const int c = nth * 64 + k * 16 + lm;
            feats[p * 384 +   0 + c] = m3[k];
            feats[p * 384 + 128 + c] = m4[k];
            feats[p * 384 + 256 + c] = m5[k];
        }
    }
    __syncthreads();

    if (t < 128) {
        const float4* wr4 = (const float4*)(fcw + (size_t)t * (3 * CC));
        float a0 = fcb[t], a1 = a0, a2 = a0, a3 = a0;
        for (int f4 = 0; f4 < 96; ++f4) {
            const float4 wv = wr4[f4];
            const float4 x0 = *(const float4*)&feats[0 * 384 + f4 * 4];
            const float4 x1 = *(const float4*)&feats[1 * 384 + f4 * 4];
            const float4 x2 = *(const float4*)&feats[2 * 384 + f4 * 4];
            const float4 x3 = *(const float4*)&feats[3 * 384 + f4 * 4];
            a0 += x0.x * wv.x + x0.y * wv.y + x0.z * wv.z + x0.w * wv.w;
            a1 += x1.x * wv.x + x1.y * wv.y + x1.z * wv.z + x1.w * wv.w;
            a2 += x2.x * wv.x + x2.y * wv.y + x2.z * wv.z + x2.w * wv.w;
            a3 += x3.x * wv.x + x3.y * wv.y + x3.z * wv.z + x3.w * wv.w;
        }
        out[(size_t)(n0 + 0) * EE + t] = a0;
        out[(size_t)(n0 + 1) * EE + t] = a1;
        out[(size_t)(n0 + 2) * EE + t] = a2;
        out[(size_t)(n0 + 3) * EE + t] = a3;
    }
}

// ---------------------------------------------------------------------------
extern "C" void kernel_launch(void* const* d_in, const int* in_sizes, int n_in,
                              void* d_out, int out_size, void* d_ws, size_t ws_size,
                              hipStream_t stream)
{
    const int*   word2news     = (const int*)d_in[0];
    const int*   word2news_len = (const int*)d_in[1];
    const int*   news_words    = (const int*)d_in[2];
    const float* table         = (const float*)d_in[3];
    const float* in_w          = (const float*)d_in[4];
    const float* in_b          = (const float*)d_in[5];
    const float* out_w         = (const float*)d_in[6];
    const float* out_b         = (const float*)d_in[7];
    const float* w3            = (const float*)d_in[8];
    const float* b3            = (const float*)d_in[9];
    const float* w4            = (const float*)d_in[10];
    const float* b4            = (const float*)d_in[11];
    const float* w5            = (const float*)d_in[12];
    const float* b5            = (const float*)d_in[13];
    const float* fcw           = (const float*)d_in[14];
    const float* fcb           = (const float*)d_in[15];

    float* out = (float*)d_out;
    u16* base  = (u16*)d_ws;
    u16* we16  = base;                                   // 2,560,000 u16 (5.12 MB)
    u16* Bpack = base + 2560000;                         //   196,608 u16
    u16* Kn16  = base + 2756608;                         // 1,048,576 u16
    u16* Wn16  = base + 3805184;                         // 1,048,576 u16 (Vn slot)
    u16* Qn16  = base + 4853760;                         // 1,048,576 u16 (11.80 MB)
    const size_t need_qn = (size_t)(4853760 + 1048576) * 2;

    if (ws_size >= need_qn) {
        // Fused path: pack_weights rides along as 48 extra blocks.
        kvqw_proj_kernel<<<NN / 8 + 48, 384, 0, stream>>>(
            table, in_w, in_b, out_w, out_b, w3, w4, w5,
            Qn16, Kn16, Wn16, Bpack);
        word_attn_wn<<<V_WORDS / WPB, 256, 0, stream>>>(
            word2news, word2news_len, Qn16, Kn16, Wn16, we16);
    } else {
        pack_weights<<<48, 256, 0, stream>>>(w3, w4, w5, Bpack);
        kv_proj_kernel<<<NN / 8, 256, 0, stream>>>(table, in_w, in_b, Kn16, Wn16);
        word_attn_kernel<<<V_WORDS / WPB, 256, 0, stream>>>(
            word2news, word2news_len, table, in_w, in_b, out_w, out_b,
            Kn16, Wn16, we16);
    }

    news_kernel<<<NN / 4, 512, 0, stream>>>(
        news_words, we16, Bpack, b3, b4, b5, fcw, fcb, out);
}

// Round 5
// 374.322 us; speedup vs baseline: 1.0048x; 1.0048x over previous
//
#include <hip/hip_runtime.h>
#include <math.h>

#define V_WORDS 20000
#define MM 32
#define EE 128
#define HH 4
#define DHH 32
#define NN 8192
#define LL 64
#define CC 128

typedef short bf16x8 __attribute__((ext_vector_type(8)));
typedef float f32x4 __attribute__((ext_vector_type(4)));
typedef unsigned short u16;
typedef unsigned int u32;

__device__ __forceinline__ u16 f2bf(float x) {
    u32 u = __float_as_uint(x);
    u32 r = (u + 0x7FFFu + ((u >> 16) & 1u)) >> 16;
    return (u16)r;
}
__device__ __forceinline__ float bflo(u32 u) { return __uint_as_float(u << 16); }
__device__ __forceinline__ float bfhi(u32 u) { return __uint_as_float(u & 0xFFFF0000u); }

// bf16 pair dot-product: 1 VALU op on gfx950 (v_dot2_f32_bf16) vs 6 for the
// unpack+fma fallback. Guarded: falls back to exact-equivalent f32 math.
#if defined(__has_builtin)
#  if __has_builtin(__builtin_amdgcn_fdot2_f32_bf16)
#    define USE_BF16_DOT2 1
#  endif
#endif
#ifdef USE_BF16_DOT2
typedef __bf16 v2bf __attribute__((ext_vector_type(2)));
#endif

__device__ __forceinline__ float dot2bf(u32 a, u32 b, float c) {
#ifdef USE_BF16_DOT2
    return __builtin_amdgcn_fdot2_f32_bf16(
        __builtin_bit_cast(v2bf, a), __builtin_bit_cast(v2bf, b), c, false);
#else
    return c + bflo(a) * bflo(b) + bfhi(a) * bfhi(b);
#endif
}

// ---------------------------------------------------------------------------
// Conv-weight pack body (shared by standalone kernel + fused-into-proj path).
// ---------------------------------------------------------------------------
__device__ __forceinline__ void pack_body(int s, int t,
                                          const float* __restrict__ w3,
                                          const float* __restrict__ w4,
                                          const float* __restrict__ w5,
                                          u16* __restrict__ Bpack)
{
    const int lane = t & 63;
    const float* src;
    int K, sl;
    if (s < 12)      { src = w3; K = 3; sl = s; }
    else if (s < 28) { src = w4; K = 4; sl = s - 12; }
    else             { src = w5; K = 5; sl = s - 28; }
    const int j  = sl >> 2;
    const int e0 = (sl & 3) * 32;

    for (int nt = (t >> 6); nt < 8; nt += 4) {
        const int c = nt * 16 + (lane & 15);
        const int kb = (lane >> 4) * 8;
        u16 vals[8];
        #pragma unroll
        for (int i = 0; i < 8; ++i) {
            const int e = e0 + kb + i;
            vals[i] = f2bf(src[(c * EE + e) * K + j]);
        }
        u16* dst = Bpack + (((size_t)s * 8 + nt) * 64 + lane) * 8;
        *(bf16x8*)dst = *(const bf16x8*)vals;
    }
}

// ---------------------------------------------------------------------------
// Kernel 0 (fallback path only): standalone weight pack.
// ---------------------------------------------------------------------------
__global__ __launch_bounds__(256)
void pack_weights(const float* __restrict__ w3,
                  const float* __restrict__ w4,
                  const float* __restrict__ w5,
                  u16* __restrict__ Bpack)
{
    pack_body(blockIdx.x, threadIdx.x, w3, w4, w5, Bpack);
}

// ---------------------------------------------------------------------------
// Kernel A (fallback, ws too small): Kn/Vn projections (R15 path).
// ---------------------------------------------------------------------------
__global__ __launch_bounds__(256)
void kv_proj_kernel(const float* __restrict__ table,
                    const float* __restrict__ in_w,
                    const float* __restrict__ in_b,
                    u16* __restrict__ Kn16, u16* __restrict__ Vn16)
{
    const int n0 = blockIdx.x * 8;
    const int t = threadIdx.x;
    __shared__ float tbl[8][EE];
    {
        const int r = t >> 5, q4 = (t & 31) * 4;
        *(float4*)&tbl[r][q4] = *(const float4*)&table[(size_t)(n0 + r) * EE + q4];
    }
    __syncthreads();

    const int sel = t >> 7;
    const int i = t & 127;
    const float* w = in_w + (size_t)(sel + 1) * EE * EE + (size_t)i * EE;
    const float bias = in_b[(sel + 1) * EE + i];

    float acc[8];
    #pragma unroll
    for (int r = 0; r < 8; ++r) acc[r] = bias;
    for (int k = 0; k < EE; k += 4) {
        const float4 wv = *(const float4*)&w[k];
        #pragma unroll
        for (int r = 0; r < 8; ++r) {
            acc[r] += tbl[r][k]     * wv.x + tbl[r][k + 1] * wv.y
                    + tbl[r][k + 2] * wv.z + tbl[r][k + 3] * wv.w;
        }
    }
    u16* dst = sel ? Vn16 : Kn16;
    #pragma unroll
    for (int r = 0; r < 8; ++r) dst[(size_t)(n0 + r) * EE + i] = f2bf(acc[r]);
}

// ---------------------------------------------------------------------------
// Kernel A'' (R23): Q/K/W projections over the 8192 distinct news rows,
// with pack_weights fused in as 48 extra blocks (kills one launch gap;
// Bpack is consumed only by news_kernel, which launches later).
// ---------------------------------------------------------------------------
__global__ __launch_bounds__(384)
void kvqw_proj_kernel(const float* __restrict__ table,
                      const float* __restrict__ in_w,
                      const float* __restrict__ in_b,
                      const float* __restrict__ out_w,
                      const float* __restrict__ out_b,
                      const float* __restrict__ w3,
                      const float* __restrict__ w4,
                      const float* __restrict__ w5,
                      u16* __restrict__ Qn16,
                      u16* __restrict__ Kn16,
                      u16* __restrict__ Wn16,
                      u16* __restrict__ Bpack)
{
    const int t = threadIdx.x;
    if (blockIdx.x >= NN / 8) {                  // fused weight-pack blocks
        if (t < 256) pack_body(blockIdx.x - NN / 8, t, w3, w4, w5, Bpack);
        return;
    }

    const int n0 = blockIdx.x * 8;
    __shared__ float tbl[8][EE];
    __shared__ float vsh[8][EE];
    if (t < 256) {
        const int r = t >> 5, q4 = (t & 31) * 4;
        *(float4*)&tbl[r][q4] = *(const float4*)&table[(size_t)(n0 + r) * EE + q4];
    }
    __syncthreads();

    const int sel = t >> 7;                 // 0 = Q, 1 = K, 2 = V
    const int i = t & 127;
    const float* w = in_w + (size_t)sel * EE * EE + (size_t)i * EE;
    const float bias = in_b[sel * EE + i];

    float acc[8];
    #pragma unroll
    for (int r = 0; r < 8; ++r) acc[r] = bias;
    for (int k = 0; k < EE; k += 4) {
        const float4 wv = *(const float4*)&w[k];
        #pragma unroll
        for (int r = 0; r < 8; ++r) {
            acc[r] += tbl[r][k]     * wv.x + tbl[r][k + 1] * wv.y
                    + tbl[r][k + 2] * wv.z + tbl[r][k + 3] * wv.w;
        }
    }
    if (sel == 0) {
        #pragma unroll
        for (int r = 0; r < 8; ++r) Qn16[(size_t)(n0 + r) * EE + i] = f2bf(acc[r]);
    } else if (sel == 1) {
        #pragma unroll
        for (int r = 0; r < 8; ++r) Kn16[(size_t)(n0 + r) * EE + i] = f2bf(acc[r]);
    } else {
        #pragma unroll
        for (int r = 0; r < 8; ++r) vsh[r][i] = acc[r];   // keep V fp32 for phase 2
    }
    __syncthreads();

    // Phase 2: Wn[r][i] = vsh[r] . out_w[i] + out_b[i]
    {
        const int g = t >> 7;
        const int r0 = g, r1 = g + 3, r2 = g + 6;       // r2 == 8 invalid for g==2
        const int r2c = (r2 < 8) ? r2 : 7;
        const float* wr = out_w + (size_t)i * EE;
        const float ob = out_b[i];
        float a0 = ob, a1 = ob, a2 = ob;
        #pragma unroll 4
        for (int k = 0; k < EE; k += 4) {
            const float4 wv = *(const float4*)&wr[k];
            a0 += vsh[r0][k]   * wv.x + vsh[r0][k+1] * wv.y
                + vsh[r0][k+2] * wv.z + vsh[r0][k+3] * wv.w;
            a1 += vsh[r1][k]   * wv.x + vsh[r1][k+1] * wv.y
                + vsh[r1][k+2] * wv.z + vsh[r1][k+3] * wv.w;
            a2 += vsh[r2c][k]   * wv.x + vsh[r2c][k+1] * wv.y
                + vsh[r2c][k+2] * wv.z + vsh[r2c][k+3] * wv.w;
        }
        Wn16[(size_t)(n0 + r0) * EE + i] = f2bf(a0);
        Wn16[(size_t)(n0 + r1) * EE + i] = f2bf(a1);
        if (r2 < 8) Wn16[(size_t)(n0 + r2) * EE + i] = f2bf(a2);
    }
}

// ---------------------------------------------------------------------------
// Kernel B (fallback): per-word attention, R15 path (unchanged).
// ---------------------------------------------------------------------------
#define WPB 8
__global__ __launch_bounds__(256, 3)
void word_attn_kernel(const int* __restrict__ word2news,
                      const int* __restrict__ word2news_len,
                      const float* __restrict__ table,
                      const float* __restrict__ in_w,
                      const float* __restrict__ in_b,
                      const float* __restrict__ out_w,
                      const float* __restrict__ out_b,
                      const u16* __restrict__ Kn16,
                      const u16* __restrict__ Vn16,
                      u16* __restrict__ we16)
{
    const int v0 = blockIdx.x * WPB;
    const int t = threadIdx.x;

    __shared__ int   rows[WPB][MM];
    __shared__ int   lenS[WPB];
    __shared__ float q[WPB][EE];
    __shared__ float qh[WPB][EE];
    __shared__ float attn[WPB][HH][MM];
    __shared__ float osh[WPB][EE];

    {
        const int w = t >> 5, m = t & 31;
        rows[w][m] = word2news[(size_t)(v0 + w) * MM + m];
        if (t < WPB) lenS[t] = word2news_len[v0 + t];
    }
    __syncthreads();

    {
        const int w = t >> 5, d0 = (t & 31) * 4;
        const int L = lenS[w];
        float4 a = {0.f, 0.f, 0.f, 0.f};
        #pragma unroll 4
        for (int m = 0; m < MM; ++m) {
            const float4 x = *(const float4*)&table[(size_t)rows[w][m] * EE + d0];
            if (m < L) { a.x += x.x; a.y += x.y; a.z += x.z; a.w += x.w; }
        }
        const float inv = (L > 0) ? 1.0f / (float)L : 0.0f;
        a.x *= inv; a.y *= inv; a.z *= inv; a.w *= inv;
        *(float4*)&q[w][d0] = a;
    }
    __syncthreads();

    {
        const int g = t >> 7, i = t & 127;
        const float* wr = in_w + (size_t)i * EE;
        float acc[4] = {0.f, 0.f, 0.f, 0.f};
        #pragma unroll 4
        for (int k = 0; k < EE; k += 4) {
            const float4 wv = *(const float4*)&wr[k];
            #pragma unroll
            for (int w4 = 0; w4 < 4; ++w4) {
                const float* qw = q[g * 4 + w4];
                acc[w4] += qw[k] * wv.x + qw[k + 1] * wv.y
                         + qw[k + 2] * wv.z + qw[k + 3] * wv.w;
            }
        }
        const float b = in_b[i];
        #pragma unroll
        for (int w4 = 0; w4 < 4; ++w4) qh[g * 4 + w4][i] = acc[w4] + b;
    }
    __syncthreads();

    {
        const int w = t >> 5, m = t & 31;
        const int L = lenS[w];
        float s[HH] = {-1e9f, -1e9f, -1e9f, -1e9f};
        if (m < L) {
            const uint4* kr = (const uint4*)(Kn16 + (size_t)rows[w][m] * EE);
            #pragma unroll 1
            for (int h = 0; h < HH; ++h) {
                float a = 0.f;
                #pragma unroll
                for (int k8 = 0; k8 < 4; ++k8) {
                    const uint4 u = kr[h * 4 + k8];
                    const float4 q0 = *(const float4*)&qh[w][h * 32 + k8 * 8];
                    const float4 q1 = *(const float4*)&qh[w][h * 32 + k8 * 8 + 4];
                    a += q0.x * bflo(u.x) + q0.y * bfhi(u.x)
                       + q0.z * bflo(u.y) + q0.w * bfhi(u.y)
                       + q1.x * bflo(u.z) + q1.y * bfhi(u.z)
                       + q1.z * bflo(u.w) + q1.w * bfhi(u.w);
                }
                s[h] = a * 0.17677669529663687f;
            }
        }
        #pragma unroll
        for (int h = 0; h < HH; ++h) {
            float mx = s[h];
            #pragma unroll
            for (int off = 16; off > 0; off >>= 1)
                mx = fmaxf(mx, __shfl_xor(mx, off, 32));
            const float ex = expf(s[h] - mx);
            float sum = ex;
            #pragma unroll
            for (int off = 16; off > 0; off >>= 1)
                sum += __shfl_xor(sum, off, 32);
            attn[w][h][m] = ex / sum;
        }
    }
    __syncthreads();

    {
        const int w = t >> 5, d0 = (t & 31) * 4;
        const int h = d0 >> 5;
        float4 a = {0.f, 0.f, 0.f, 0.f};
        #pragma unroll 4
        for (int m = 0; m < MM; ++m) {
            const float aw = attn[w][h][m];
            const u32* vr = (const u32*)(Vn16 + (size_t)rows[w][m] * EE + d0);
            const u32 u0 = vr[0], u1 = vr[1];
            a.x += aw * bflo(u0); a.y += aw * bfhi(u0);
            a.z += aw * bflo(u1); a.w += aw * bfhi(u1);
        }
        *(float4*)&osh[w][d0] = a;
    }
    __syncthreads();

    {
        const int g = t >> 7, i = t & 127;
        const float* wr = out_w + (size_t)i * EE;
        float acc[4] = {0.f, 0.f, 0.f, 0.f};
        #pragma unroll 4
        for (int k = 0; k < EE; k += 4) {
            const float4 wv = *(const float4*)&wr[k];
            #pragma unroll
            for (int w4 = 0; w4 < 4; ++w4) {
                const float* ow = osh[g * 4 + w4];
                acc[w4] += ow[k] * wv.x + ow[k + 1] * wv.y
                         + ow[k + 2] * wv.z + ow[k + 3] * wv.w;
            }
        }
        const float b = out_b[i];
        #pragma unroll
        for (int w4 = 0; w4 < 4; ++w4) {
            const int w = g * 4 + w4;
            we16[(size_t)(v0 + w) * EE + i] =
                (lenS[w] > 0) ? f2bf(acc[w4] + b) : (u16)0;
        }
    }
}

// ---------------------------------------------------------------------------
// Kernel B'' (R24): R22 barrier structure RESTORED (phase-aligned gathers
// keep the per-phase working set = one 2MB array, fitting per-XCD L2;
// R23's barrier-free variant mixed 6MB across phases and regressed 8%).
// New in R24: K-row REGISTER PREFETCH — the lane's 16x uint4 K row is
// issued (exec-masked m<L) BEFORE the Q-mean gather loop, so its ~200-400cy
// L2 latency hides under the Q-mean chain; the score phase then runs on
// registers with no memory wait. expf -> __expf (proven same absmax, R23).
// ---------------------------------------------------------------------------
__global__ __launch_bounds__(256, 3)
void word_attn_wn(const int* __restrict__ word2news,
                  const int* __restrict__ word2news_len,
                  const u16* __restrict__ Qn16,
                  const u16* __restrict__ Kn16,
                  const u16* __restrict__ Wn16,
                  u16* __restrict__ we16)
{
    const int v0 = blockIdx.x * WPB;
    const int t = threadIdx.x;
    const int w = t >> 5, m = t & 31;

    __shared__ int   rows[WPB][MM];
    __shared__ int   lenS[WPB];
    __shared__ __align__(16) u32 qhp[WPB][EE / 2];   // bf16-pair packed query
    __shared__ float attn[WPB][HH][MM];

    {
        rows[w][m] = word2news[(size_t)(v0 + w) * MM + m];
        if (t < WPB) lenS[t] = word2news_len[v0 + t];
    }
    __syncthreads();

    const int L = lenS[w];

    // K-row prefetch: issue all 16 uint4 (256B) of this lane's K row now;
    // results are consumed only in the score phase, so the loads' latency
    // overlaps the entire Q-mean gather chain below. Masked to m<L so
    // gather traffic matches R22 exactly.
    uint4 kq[16];
    if (m < L) {
        const uint4* kr = (const uint4*)(Kn16 + (size_t)rows[w][m] * EE);
        #pragma unroll
        for (int i = 0; i < 16; ++i) kq[i] = kr[i];
    }

    // qh = mean of gathered Qn rows (bias included; exact — weights sum to 1).
    // Loop to L only (uniform per 32-lane group); pack result as bf16 pairs.
    {
        const int d0 = m * 4;
        float4 a = {0.f, 0.f, 0.f, 0.f};
        #pragma unroll 4
        for (int mm = 0; mm < L; ++mm) {
            const uint2 u = *(const uint2*)(Qn16 + (size_t)rows[w][mm] * EE + d0);
            a.x += bflo(u.x); a.y += bfhi(u.x);
            a.z += bflo(u.y); a.w += bfhi(u.y);
        }
        const float inv = (L > 0) ? 1.0f / (float)L : 0.0f;
        a.x *= inv; a.y *= inv; a.z *= inv; a.w *= inv;
        qhp[w][(d0 >> 1) + 0] = (u32)f2bf(a.x) | ((u32)f2bf(a.y) << 16);
        qhp[w][(d0 >> 1) + 1] = (u32)f2bf(a.z) | ((u32)f2bf(a.w) << 16);
    }
    __syncthreads();

    // scores from prefetched registers + softmax over m.
    {
        float s[HH] = {-1e9f, -1e9f, -1e9f, -1e9f};
        if (m < L) {
            const u32* qp = qhp[w];
            #pragma unroll
            for (int h = 0; h < HH; ++h) {
                float a = 0.f;
                #pragma unroll
                for (int k8 = 0; k8 < 4; ++k8) {
                    const uint4 u  = kq[h * 4 + k8];
                    const uint4 qq = *(const uint4*)&qp[h * 16 + k8 * 4];
                    a = dot2bf(u.x, qq.x, a);
                    a = dot2bf(u.y, qq.y, a);
                    a = dot2bf(u.z, qq.z, a);
                    a = dot2bf(u.w, qq.w, a);
                }
                s[h] = a * 0.17677669529663687f;
            }
        }
        #pragma unroll
        for (int h = 0; h < HH; ++h) {
            float mx = s[h];
            #pragma unroll
            for (int off = 16; off > 0; off >>= 1)
                mx = fmaxf(mx, __shfl_xor(mx, off, 32));
            const float ex = __expf(s[h] - mx);    // masked lanes underflow to 0
            float sum = ex;
            #pragma unroll
            for (int off = 16; off > 0; off >>= 1)
                sum += __shfl_xor(sum, off, 32);
            attn[w][h][m] = ex / sum;
        }
    }
    __syncthreads();

    // we = sum_{m<L} attn_m * Wn[rows[m]]  (out-proj + bias pre-folded into
    // Wn; attn==0 exactly for m>=L so the truncation is exact).
    {
        const int d0 = m * 4;
        const int h = d0 >> 5;
        float4 a = {0.f, 0.f, 0.f, 0.f};
        #pragma unroll 4
        for (int mm = 0; mm < L; ++mm) {
            const float aw = attn[w][h][mm];
            const uint2 u = *(const uint2*)(Wn16 + (size_t)rows[w][mm] * EE + d0);
            a.x += aw * bflo(u.x); a.y += aw * bfhi(u.x);
            a.z += aw * bflo(u.y); a.w += aw * bfhi(u.y);
        }
        u32 lo = 0u, hi = 0u;
        if (L > 0) {
            lo = (u32)f2bf(a.x) | ((u32)f2bf(a.y) << 16);
            hi = (u32)f2bf(a.z) | ((u32)f2bf(a.w) << 16);
        }
        u32* dst = (u32*)(we16 + (size_t)(v0 + w) * EE + d0);
        dst[0] = lo; dst[1] = hi;
    }
}

// ---------------------------------------------------------------------------
// Kernel 2: implicit-GEMM conv — R16/R18 MEASURED OPTIMUM, unchanged.
// (#pragma unroll 2; full unroll spills — R20 measured 14x regression.)
// ---------------------------------------------------------------------------
#define DSTRIDE 136              // u16 per doc row (16B-aligned, 68 words)
#define DOCSZ   (68 * DSTRIDE)   // u16 per doc (64 data rows + 4 zero rows)

template<int NSL, int SBASE, int NP>
__device__ __forceinline__ void conv_g2(const u16* __restrict__ lds,
                                        const u16* __restrict__ Bpack,
                                        const float* __restrict__ bk,
                                        int p, int nth, int l,
                                        float (&mxout)[4])
{
    f32x4 acc[4][4];
    #pragma unroll
    for (int mt = 0; mt < 4; ++mt)
        #pragma unroll
        for (int k = 0; k < 4; ++k)
            acc[mt][k] = (f32x4){0.f, 0.f, 0.f, 0.f};

    const int lm = l & 15;
    const int g  = l >> 4;
    const u16* bbase = Bpack + ((size_t)SBASE * 8 + nth * 4) * 512 + l * 8;
    const u16* abase = lds + (size_t)p * DOCSZ;

    #pragma unroll 2
    for (int s = 0; s < NSL; ++s) {
        const int j  = s >> 2;
        const int e0 = (s & 3) * 32;

        bf16x8 b[4];
        #pragma unroll
        for (int k = 0; k < 4; ++k)
            b[k] = *(const bf16x8*)(bbase + s * 4096 + k * 512);

        const u16* arow = abase + (lm + j) * DSTRIDE + e0 + g * 8;
        bf16x8 a[4];
        #pragma unroll
        for (int mt = 0; mt < 4; ++mt)
            a[mt] = *(const bf16x8*)(arow + mt * (16 * DSTRIDE));

        #pragma unroll
        for (int mt = 0; mt < 4; ++mt)
            #pragma unroll
            for (int k = 0; k < 4; ++k)
                acc[mt][k] = __builtin_amdgcn_mfma_f32_16x16x32_bf16(a[mt], b[k], acc[mt][k], 0, 0, 0);
    }

    #pragma unroll
    for (int k = 0; k < 4; ++k) {
        const int c = nth * 64 + k * 16 + lm;
        const float bias = bk[c];
        float mx = 0.0f;                     // relu output >= 0
        #pragma unroll
        for (int mt = 0; mt < 4; ++mt) {
            #pragma unroll
            for (int r = 0; r < 4; ++r) {
                const int pos = 16 * mt + g * 4 + r;
                const float y = fmaxf(acc[mt][k][r] + bias, 0.0f);
                if (pos < NP) mx = fmaxf(mx, y);
            }
        }
        mx = fmaxf(mx, __shfl_xor(mx, 16));
        mx = fmaxf(mx, __shfl_xor(mx, 32));
        mxout[k] = mx;
    }
}

__global__ __launch_bounds__(512, 4)
void news_kernel(const int* __restrict__ news_words,
                 const u16* __restrict__ we16,
                 const u16* __restrict__ Bpack,
                 const float* __restrict__ b3,
                 const float* __restrict__ b4,
                 const float* __restrict__ b5,
                 const float* __restrict__ fcw, const float* __restrict__ fcb,
                 float* __restrict__ out)
{
    const int n0 = blockIdx.x * 4;
    const int t = threadIdx.x;
    const int w = t >> 6, l = t & 63;
    const int p = w >> 1, nth = w & 1;

    __shared__ u16 lds[4 * DOCSZ];           // 73,984 B; feats alias after convs
    __shared__ int rows[4 * LL];

    if (t < 4 * LL) rows[t] = news_words[(size_t)n0 * LL + t];
    __syncthreads();

    {
        const uint4* weU = (const uint4*)we16;     // 16 uint4 per doc row
        uint4* ldsU = (uint4*)lds;                 // doc stride 1156 uint4
        for (int idx = t; idx < 4096; idx += 512) {
            const int d = idx >> 10, rem = idx & 1023;
            const int row = rem >> 4, c4 = rem & 15;
            ldsU[d * 1156 + row * 17 + c4] = weU[(size_t)rows[d * 64 + row] * 16 + c4];
        }
        if (t < 256) {                             // 4 docs x 4 pad rows x 16
            const int d = t >> 6, rem = t & 63;
            const int row = 64 + (rem >> 4), c4 = rem & 15;
            ldsU[d * 1156 + row * 17 + c4] = (uint4){0u, 0u, 0u, 0u};
        }
    }
    __syncthreads();

    float m3[4], m4[4], m5[4];
    conv_g2<12,  0, 62>(lds, Bpack, b3, p, nth, l, m3);
    conv_g2<16, 12, 61>(lds, Bpack, b4, p, nth, l, m4);
    conv_g2<20, 28, 60>(lds, Bpack, b5, p, nth, l, m5);
    __syncthreads();                          // docs dead beyond this point

    float* feats = (float*)lds;               // [4][384] aliases doc buffer
    if ((l >> 4) == 0) {
        const int lm = l & 15;
        #pragma unroll
        for (int k = 0; k < 4; ++k) {
            const int c = nth * 64 + k * 16 + lm;
            feats[p * 384 +   0 + c] = m3[k];
            feats[p * 384 + 128 + c] = m4[k];
            feats[p * 384 + 256 + c] = m5[k];
        }
    }
    __syncthreads();

    if (t < 128) {
        const float4* wr4 = (const float4*)(fcw + (size_t)t * (3 * CC));
        float a0 = fcb[t], a1 = a0, a2 = a0, a3 = a0;
        for (int f4 = 0; f4 < 96; ++f4) {
            const float4 wv = wr4[f4];
            const float4 x0 = *(const float4*)&feats[0 * 384 + f4 * 4];
            const float4 x1 = *(const float4*)&feats[1 * 384 + f4 * 4];
            const float4 x2 = *(const float4*)&feats[2 * 384 + f4 * 4];
            const float4 x3 = *(const float4*)&feats[3 * 384 + f4 * 4];
            a0 += x0.x * wv.x + x0.y * wv.y + x0.z * wv.z + x0.w * wv.w;
            a1 += x1.x * wv.x + x1.y * wv.y + x1.z * wv.z + x1.w * wv.w;
            a2 += x2.x * wv.x + x2.y * wv.y + x2.z * wv.z + x2.w * wv.w;
            a3 += x3.x * wv.x + x3.y * wv.y + x3.z * wv.z + x3.w * wv.w;
        }
        out[(size_t)(n0 + 0) * EE + t] = a0;
        out[(size_t)(n0 + 1) * EE + t] = a1;
        out[(size_t)(n0 + 2) * EE + t] = a2;
        out[(size_t)(n0 + 3) * EE + t] = a3;
    }
}

// ---------------------------------------------------------------------------
extern "C" void kernel_launch(void* const* d_in, const int* in_sizes, int n_in,
                              void* d_out, int out_size, void* d_ws, size_t ws_size,
                              hipStream_t stream)
{
    const int*   word2news     = (const int*)d_in[0];
    const int*   word2news_len = (const int*)d_in[1];
    const int*   news_words    = (const int*)d_in[2];
    const float* table         = (const float*)d_in[3];
    const float* in_w          = (const float*)d_in[4];
    const float* in_b          = (const float*)d_in[5];
    const float* out_w         = (const float*)d_in[6];
    const float* out_b         = (const float*)d_in[7];
    const float* w3            = (const float*)d_in[8];
    const float* b3            = (const float*)d_in[9];
    const float* w4            = (const float*)d_in[10];
    const float* b4            = (const float*)d_in[11];
    const float* w5            = (const float*)d_in[12];
    const float* b5            = (const float*)d_in[13];
    const float* fcw           = (const float*)d_in[14];
    const float* fcb           = (const float*)d_in[15];

    float* out = (float*)d_out;
    u16* base  = (u16*)d_ws;
    u16* we16  = base;                                   // 2,560,000 u16 (5.12 MB)
    u16* Bpack = base + 2560000;                         //   196,608 u16
    u16* Kn16  = base + 2756608;                         // 1,048,576 u16
    u16* Wn16  = base + 3805184;                         // 1,048,576 u16 (Vn slot)
    u16* Qn16  = base + 4853760;                         // 1,048,576 u16 (11.80 MB)
    const size_t need_qn = (size_t)(4853760 + 1048576) * 2;

    if (ws_size >= need_qn) {
        // Fused path: pack_weights rides along as 48 extra blocks.
        kvqw_proj_kernel<<<NN / 8 + 48, 384, 0, stream>>>(
            table, in_w, in_b, out_w, out_b, w3, w4, w5,
            Qn16, Kn16, Wn16, Bpack);
        word_attn_wn<<<V_WORDS / WPB, 256, 0, stream>>>(
            word2news, word2news_len, Qn16, Kn16, Wn16, we16);
    } else {
        pack_weights<<<48, 256, 0, stream>>>(w3, w4, w5, Bpack);
        kv_proj_kernel<<<NN / 8, 256, 0, stream>>>(table, in_w, in_b, Kn16, Wn16);
        word_attn_kernel<<<V_WORDS / WPB, 256, 0, stream>>>(
            word2news, word2news_len, table, in_w, in_b, out_w, out_b,
            Kn16, Wn16, we16);
    }

    news_kernel<<<NN / 4, 512, 0, stream>>>(
        news_words, we16, Bpack, b3, b4, b5, fcw, fcb, out);
}

// Round 6
// 373.018 us; speedup vs baseline: 1.0083x; 1.0035x over previous
//
#include <hip/hip_runtime.h>
#include <math.h>

#define V_WORDS 20000
#define MM 32
#define EE 128
#define HH 4
#define DHH 32
#define NN 8192
#define LL 64
#define CC 128

typedef short bf16x8 __attribute__((ext_vector_type(8)));
typedef float f32x4 __attribute__((ext_vector_type(4)));
typedef unsigned short u16;
typedef unsigned int u32;

__device__ __forceinline__ u16 f2bf(float x) {
    u32 u = __float_as_uint(x);
    u32 r = (u + 0x7FFFu + ((u >> 16) & 1u)) >> 16;
    return (u16)r;
}
__device__ __forceinline__ float bflo(u32 u) { return __uint_as_float(u << 16); }
__device__ __forceinline__ float bfhi(u32 u) { return __uint_as_float(u & 0xFFFF0000u); }

// bf16 pair dot-product: 1 VALU op on gfx950 (v_dot2_f32_bf16) vs 6 for the
// unpack+fma fallback. Guarded: falls back to exact-equivalent f32 math.
#if defined(__has_builtin)
#  if __has_builtin(__builtin_amdgcn_fdot2_f32_bf16)
#    define USE_BF16_DOT2 1
#  endif
#endif
#ifdef USE_BF16_DOT2
typedef __bf16 v2bf __attribute__((ext_vector_type(2)));
#endif

__device__ __forceinline__ float dot2bf(u32 a, u32 b, float c) {
#ifdef USE_BF16_DOT2
    return __builtin_amdgcn_fdot2_f32_bf16(
        __builtin_bit_cast(v2bf, a), __builtin_bit_cast(v2bf, b), c, false);
#else
    return c + bflo(a) * bflo(b) + bfhi(a) * bfhi(b);
#endif
}

// ---------------------------------------------------------------------------
// Kernel 0: pack conv weights into bf16 MFMA B-fragment order (unchanged).
// ---------------------------------------------------------------------------
__global__ __launch_bounds__(256)
void pack_weights(const float* __restrict__ w3,
                  const float* __restrict__ w4,
                  const float* __restrict__ w5,
                  u16* __restrict__ Bpack)
{
    const int s = blockIdx.x;
    const int t = threadIdx.x;
    const int lane = t & 63;

    const float* src;
    int K, sl;
    if (s < 12)      { src = w3; K = 3; sl = s; }
    else if (s < 28) { src = w4; K = 4; sl = s - 12; }
    else             { src = w5; K = 5; sl = s - 28; }
    const int j  = sl >> 2;
    const int e0 = (sl & 3) * 32;

    for (int nt = (t >> 6); nt < 8; nt += 4) {
        const int c = nt * 16 + (lane & 15);
        const int kb = (lane >> 4) * 8;
        u16 vals[8];
        #pragma unroll
        for (int i = 0; i < 8; ++i) {
            const int e = e0 + kb + i;
            vals[i] = f2bf(src[(c * EE + e) * K + j]);
        }
        u16* dst = Bpack + (((size_t)s * 8 + nt) * 64 + lane) * 8;
        *(bf16x8*)dst = *(const bf16x8*)vals;
    }
}

// ---------------------------------------------------------------------------
// Kernel A (fallback, ws too small): Kn/Vn projections (R15 path).
// ---------------------------------------------------------------------------
__global__ __launch_bounds__(256)
void kv_proj_kernel(const float* __restrict__ table,
                    const float* __restrict__ in_w,
                    const float* __restrict__ in_b,
                    u16* __restrict__ Kn16, u16* __restrict__ Vn16)
{
    const int n0 = blockIdx.x * 8;
    const int t = threadIdx.x;
    __shared__ float tbl[8][EE];
    {
        const int r = t >> 5, q4 = (t & 31) * 4;
        *(float4*)&tbl[r][q4] = *(const float4*)&table[(size_t)(n0 + r) * EE + q4];
    }
    __syncthreads();

    const int sel = t >> 7;
    const int i = t & 127;
    const float* w = in_w + (size_t)(sel + 1) * EE * EE + (size_t)i * EE;
    const float bias = in_b[(sel + 1) * EE + i];

    float acc[8];
    #pragma unroll
    for (int r = 0; r < 8; ++r) acc[r] = bias;
    for (int k = 0; k < EE; k += 4) {
        const float4 wv = *(const float4*)&w[k];
        #pragma unroll
        for (int r = 0; r < 8; ++r) {
            acc[r] += tbl[r][k]     * wv.x + tbl[r][k + 1] * wv.y
                    + tbl[r][k + 2] * wv.z + tbl[r][k + 3] * wv.w;
        }
    }
    u16* dst = sel ? Vn16 : Kn16;
    #pragma unroll
    for (int r = 0; r < 8; ++r) dst[(size_t)(n0 + r) * EE + i] = f2bf(acc[r]);
}

// ---------------------------------------------------------------------------
// Kernel A'' (R19 form, R22-proven): Q/K/W projections over 8192 news rows.
// ---------------------------------------------------------------------------
__global__ __launch_bounds__(384)
void kvqw_proj_kernel(const float* __restrict__ table,
                      const float* __restrict__ in_w,
                      const float* __restrict__ in_b,
                      const float* __restrict__ out_w,
                      const float* __restrict__ out_b,
                      u16* __restrict__ Qn16,
                      u16* __restrict__ Kn16,
                      u16* __restrict__ Wn16)
{
    const int n0 = blockIdx.x * 8;
    const int t = threadIdx.x;
    __shared__ float tbl[8][EE];
    __shared__ float vsh[8][EE];
    if (t < 256) {
        const int r = t >> 5, q4 = (t & 31) * 4;
        *(float4*)&tbl[r][q4] = *(const float4*)&table[(size_t)(n0 + r) * EE + q4];
    }
    __syncthreads();

    const int sel = t >> 7;                 // 0 = Q, 1 = K, 2 = V
    const int i = t & 127;
    const float* w = in_w + (size_t)sel * EE * EE + (size_t)i * EE;
    const float bias = in_b[sel * EE + i];

    float acc[8];
    #pragma unroll
    for (int r = 0; r < 8; ++r) acc[r] = bias;
    for (int k = 0; k < EE; k += 4) {
        const float4 wv = *(const float4*)&w[k];
        #pragma unroll
        for (int r = 0; r < 8; ++r) {
            acc[r] += tbl[r][k]     * wv.x + tbl[r][k + 1] * wv.y
                    + tbl[r][k + 2] * wv.z + tbl[r][k + 3] * wv.w;
        }
    }
    if (sel == 0) {
        #pragma unroll
        for (int r = 0; r < 8; ++r) Qn16[(size_t)(n0 + r) * EE + i] = f2bf(acc[r]);
    } else if (sel == 1) {
        #pragma unroll
        for (int r = 0; r < 8; ++r) Kn16[(size_t)(n0 + r) * EE + i] = f2bf(acc[r]);
    } else {
        #pragma unroll
        for (int r = 0; r < 8; ++r) vsh[r][i] = acc[r];   // keep V fp32 for phase 2
    }
    __syncthreads();

    // Phase 2: Wn[r][i] = vsh[r] . out_w[i] + out_b[i]
    {
        const int g = t >> 7;
        const int r0 = g, r1 = g + 3, r2 = g + 6;       // r2 == 8 invalid for g==2
        const int r2c = (r2 < 8) ? r2 : 7;
        const float* wr = out_w + (size_t)i * EE;
        const float ob = out_b[i];
        float a0 = ob, a1 = ob, a2 = ob;
        #pragma unroll 4
        for (int k = 0; k < EE; k += 4) {
            const float4 wv = *(const float4*)&wr[k];
            a0 += vsh[r0][k]   * wv.x + vsh[r0][k+1] * wv.y
                + vsh[r0][k+2] * wv.z + vsh[r0][k+3] * wv.w;
            a1 += vsh[r1][k]   * wv.x + vsh[r1][k+1] * wv.y
                + vsh[r1][k+2] * wv.z + vsh[r1][k+3] * wv.w;
            a2 += vsh[r2c][k]   * wv.x + vsh[r2c][k+1] * wv.y
                + vsh[r2c][k+2] * wv.z + vsh[r2c][k+3] * wv.w;
        }
        Wn16[(size_t)(n0 + r0) * EE + i] = f2bf(a0);
        Wn16[(size_t)(n0 + r1) * EE + i] = f2bf(a1);
        if (r2 < 8) Wn16[(size_t)(n0 + r2) * EE + i] = f2bf(a2);
    }
}

// ---------------------------------------------------------------------------
// Kernel B (fallback): per-word attention, R15 path (unchanged).
// ---------------------------------------------------------------------------
#define WPB 8
__global__ __launch_bounds__(256, 3)
void word_attn_kernel(const int* __restrict__ word2news,
                      const int* __restrict__ word2news_len,
                      const float* __restrict__ table,
                      const float* __restrict__ in_w,
                      const float* __restrict__ in_b,
                      const float* __restrict__ out_w,
                      const float* __restrict__ out_b,
                      const u16* __restrict__ Kn16,
                      const u16* __restrict__ Vn16,
                      u16* __restrict__ we16)
{
    const int v0 = blockIdx.x * WPB;
    const int t = threadIdx.x;

    __shared__ int   rows[WPB][MM];
    __shared__ int   lenS[WPB];
    __shared__ float q[WPB][EE];
    __shared__ float qh[WPB][EE];
    __shared__ float attn[WPB][HH][MM];
    __shared__ float osh[WPB][EE];

    {
        const int w = t >> 5, m = t & 31;
        rows[w][m] = word2news[(size_t)(v0 + w) * MM + m];
        if (t < WPB) lenS[t] = word2news_len[v0 + t];
    }
    __syncthreads();

    {
        const int w = t >> 5, d0 = (t & 31) * 4;
        const int L = lenS[w];
        float4 a = {0.f, 0.f, 0.f, 0.f};
        #pragma unroll 4
        for (int m = 0; m < MM; ++m) {
            const float4 x = *(const float4*)&table[(size_t)rows[w][m] * EE + d0];
            if (m < L) { a.x += x.x; a.y += x.y; a.z += x.z; a.w += x.w; }
        }
        const float inv = (L > 0) ? 1.0f / (float)L : 0.0f;
        a.x *= inv; a.y *= inv; a.z *= inv; a.w *= inv;
        *(float4*)&q[w][d0] = a;
    }
    __syncthreads();

    {
        const int g = t >> 7, i = t & 127;
        const float* wr = in_w + (size_t)i * EE;
        float acc[4] = {0.f, 0.f, 0.f, 0.f};
        #pragma unroll 4
        for (int k = 0; k < EE; k += 4) {
            const float4 wv = *(const float4*)&wr[k];
            #pragma unroll
            for (int w4 = 0; w4 < 4; ++w4) {
                const float* qw = q[g * 4 + w4];
                acc[w4] += qw[k] * wv.x + qw[k + 1] * wv.y
                         + qw[k + 2] * wv.z + qw[k + 3] * wv.w;
            }
        }
        const float b = in_b[i];
        #pragma unroll
        for (int w4 = 0; w4 < 4; ++w4) qh[g * 4 + w4][i] = acc[w4] + b;
    }
    __syncthreads();

    {
        const int w = t >> 5, m = t & 31;
        const int L = lenS[w];
        float s[HH] = {-1e9f, -1e9f, -1e9f, -1e9f};
        if (m < L) {
            const uint4* kr = (const uint4*)(Kn16 + (size_t)rows[w][m] * EE);
            #pragma unroll 1
            for (int h = 0; h < HH; ++h) {
                float a = 0.f;
                #pragma unroll
                for (int k8 = 0; k8 < 4; ++k8) {
                    const uint4 u = kr[h * 4 + k8];
                    const float4 q0 = *(const float4*)&qh[w][h * 32 + k8 * 8];
                    const float4 q1 = *(const float4*)&qh[w][h * 32 + k8 * 8 + 4];
                    a += q0.x * bflo(u.x) + q0.y * bfhi(u.x)
                       + q0.z * bflo(u.y) + q0.w * bfhi(u.y)
                       + q1.x * bflo(u.z) + q1.y * bfhi(u.z)
                       + q1.z * bflo(u.w) + q1.w * bfhi(u.w);
                }
                s[h] = a * 0.17677669529663687f;
            }
        }
        #pragma unroll
        for (int h = 0; h < HH; ++h) {
            float mx = s[h];
            #pragma unroll
            for (int off = 16; off > 0; off >>= 1)
                mx = fmaxf(mx, __shfl_xor(mx, off, 32));
            const float ex = expf(s[h] - mx);
            float sum = ex;
            #pragma unroll
            for (int off = 16; off > 0; off >>= 1)
                sum += __shfl_xor(sum, off, 32);
            attn[w][h][m] = ex / sum;
        }
    }
    __syncthreads();

    {
        const int w = t >> 5, d0 = (t & 31) * 4;
        const int h = d0 >> 5;
        float4 a = {0.f, 0.f, 0.f, 0.f};
        #pragma unroll 4
        for (int m = 0; m < MM; ++m) {
            const float aw = attn[w][h][m];
            const u32* vr = (const u32*)(Vn16 + (size_t)rows[w][m] * EE + d0);
            const u32 u0 = vr[0], u1 = vr[1];
            a.x += aw * bflo(u0); a.y += aw * bfhi(u0);
            a.z += aw * bflo(u1); a.w += aw * bfhi(u1);
        }
        *(float4*)&osh[w][d0] = a;
    }
    __syncthreads();

    {
        const int g = t >> 7, i = t & 127;
        const float* wr = out_w + (size_t)i * EE;
        float acc[4] = {0.f, 0.f, 0.f, 0.f};
        #pragma unroll 4
        for (int k = 0; k < EE; k += 4) {
            const float4 wv = *(const float4*)&wr[k];
            #pragma unroll
            for (int w4 = 0; w4 < 4; ++w4) {
                const float* ow = osh[g * 4 + w4];
                acc[w4] += ow[k] * wv.x + ow[k + 1] * wv.y
                         + ow[k + 2] * wv.z + ow[k + 3] * wv.w;
            }
        }
        const float b = out_b[i];
        #pragma unroll
        for (int w4 = 0; w4 < 4; ++w4) {
            const int w = g * 4 + w4;
            we16[(size_t)(v0 + w) * EE + i] =
                (lenS[w] > 0) ? f2bf(acc[w4] + b) : (u16)0;
        }
    }
}

// ---------------------------------------------------------------------------
// Kernel B'' (R25): one 64-lane WAVE per word (WPW=4 words/block). The two
// 32-lane halves split even/odd rows in the Q-mean and Wn gathers (trip L/2,
// combined with one shfl_xor(32)) and split head-pairs in the score phase
// (128B K-read per lane instead of 256B). Halves the latency-critical gather
// chains that R21/R22 proved binding; R24's issue-order prefetch inverted
// under vmcnt semantics and is NOT used. Barriers kept (R23: phase-aligned
// gathers keep the per-phase working set = one 2MB array = L2-resident).
// Exactness: odd-tail guarded in Q-mean; attn[ri>=L]==0 exactly in Wn;
// ri <= 31 always since mm <= L-1 <= 30 on the last pair step.
// ---------------------------------------------------------------------------
#define WPW 4
__global__ __launch_bounds__(256, 3)
void word_attn_wn(const int* __restrict__ word2news,
                  const int* __restrict__ word2news_len,
                  const u16* __restrict__ Qn16,
                  const u16* __restrict__ Kn16,
                  const u16* __restrict__ Wn16,
                  u16* __restrict__ we16)
{
    const int v0 = blockIdx.x * WPW;
    const int t = threadIdx.x;
    const int w   = t >> 6;        // word slot: one wave per word
    const int l   = t & 63;
    const int h2  = l >> 5;        // half 0/1
    const int m32 = l & 31;

    __shared__ int   rows[WPW][MM];
    __shared__ int   lenS[WPW];
    __shared__ __align__(16) u32 qhp[WPW][EE / 2];   // bf16-pair packed query
    __shared__ float attn[WPW][HH][MM];

    {
        if (t < WPW * MM) rows[t >> 5][t & 31] = word2news[(size_t)v0 * MM + t];
        if (t < WPW) lenS[t] = word2news_len[v0 + t];
    }
    __syncthreads();

    const int L  = lenS[w];
    const int d0 = m32 * 4;

    // qh = mean of gathered Qn rows; halves take even/odd rows (chain L/2).
    {
        float4 a = {0.f, 0.f, 0.f, 0.f};
        #pragma unroll 4
        for (int mm = 0; mm < L; mm += 2) {
            const int ri = mm + h2;
            if (ri < L) {
                const uint2 u = *(const uint2*)(Qn16 + (size_t)rows[w][ri] * EE + d0);
                a.x += bflo(u.x); a.y += bfhi(u.x);
                a.z += bflo(u.y); a.w += bfhi(u.y);
            }
        }
        a.x += __shfl_xor(a.x, 32);
        a.y += __shfl_xor(a.y, 32);
        a.z += __shfl_xor(a.z, 32);
        a.w += __shfl_xor(a.w, 32);
        const float inv = (L > 0) ? 1.0f / (float)L : 0.0f;
        if (h2 == 0) {
            qhp[w][(d0 >> 1) + 0] = (u32)f2bf(a.x * inv) | ((u32)f2bf(a.y * inv) << 16);
            qhp[w][(d0 >> 1) + 1] = (u32)f2bf(a.z * inv) | ((u32)f2bf(a.w * inv) << 16);
        }
    }
    __syncthreads();

    // scores: each half does 2 heads of its row (8x uint4 = 128B K-read).
    {
        float s[2] = {-1e9f, -1e9f};
        if (m32 < L) {
            const uint4* kr = (const uint4*)(Kn16 + (size_t)rows[w][m32] * EE);
            uint4 kq[8];
            #pragma unroll
            for (int i = 0; i < 8; ++i) kq[i] = kr[h2 * 8 + i];
            const u32* qp = qhp[w];
            #pragma unroll
            for (int hl = 0; hl < 2; ++hl) {
                const int h = h2 * 2 + hl;
                float a = 0.f;
                #pragma unroll
                for (int k8 = 0; k8 < 4; ++k8) {
                    const uint4 u  = kq[hl * 4 + k8];
                    const uint4 qq = *(const uint4*)&qp[h * 16 + k8 * 4];
                    a = dot2bf(u.x, qq.x, a);
                    a = dot2bf(u.y, qq.y, a);
                    a = dot2bf(u.z, qq.z, a);
                    a = dot2bf(u.w, qq.w, a);
                }
                s[hl] = a * 0.17677669529663687f;
            }
        }
        #pragma unroll
        for (int hl = 0; hl < 2; ++hl) {
            float mx = s[hl];
            #pragma unroll
            for (int off = 16; off > 0; off >>= 1)
                mx = fmaxf(mx, __shfl_xor(mx, off, 32));
            const float ex = __expf(s[hl] - mx);   // masked lanes underflow to 0
            float sum = ex;
            #pragma unroll
            for (int off = 16; off > 0; off >>= 1)
                sum += __shfl_xor(sum, off, 32);
            attn[w][h2 * 2 + hl][m32] = ex / sum;
        }
    }
    __syncthreads();

    // we = sum_m attn_m * Wn[rows[m]]; halves take even/odd rows.
    {
        const int h = m32 >> 3;
        float4 a = {0.f, 0.f, 0.f, 0.f};
        #pragma unroll 4
        for (int mm = 0; mm < L; mm += 2) {
            const int ri = mm + h2;            // ri<=31; attn==0 for ri>=L
            const float aw = attn[w][h][ri];
            const uint2 u = *(const uint2*)(Wn16 + (size_t)rows[w][ri] * EE + d0);
            a.x += aw * bflo(u.x); a.y += aw * bfhi(u.x);
            a.z += aw * bflo(u.y); a.w += aw * bfhi(u.y);
        }
        a.x += __shfl_xor(a.x, 32);
        a.y += __shfl_xor(a.y, 32);
        a.z += __shfl_xor(a.z, 32);
        a.w += __shfl_xor(a.w, 32);
        if (h2 == 0) {
            u32 lo = 0u, hi = 0u;
            if (L > 0) {
                lo = (u32)f2bf(a.x) | ((u32)f2bf(a.y) << 16);
                hi = (u32)f2bf(a.z) | ((u32)f2bf(a.w) << 16);
            }
            u32* dst = (u32*)(we16 + (size_t)(v0 + w) * EE + d0);
            dst[0] = lo; dst[1] = hi;
        }
    }
}

// ---------------------------------------------------------------------------
// Kernel 2: implicit-GEMM conv — R16/R18 MEASURED OPTIMUM, unchanged.
// (#pragma unroll 2; full unroll spills — R20 measured 14x regression.)
// ---------------------------------------------------------------------------
#define DSTRIDE 136              // u16 per doc row (16B-aligned, 68 words)
#define DOCSZ   (68 * DSTRIDE)   // u16 per doc (64 data rows + 4 zero rows)

template<int NSL, int SBASE, int NP>
__device__ __forceinline__ void conv_g2(const u16* __restrict__ lds,
                                        const u16* __restrict__ Bpack,
                                        const float* __restrict__ bk,
                                        int p, int nth, int l,
                                        float (&mxout)[4])
{
    f32x4 acc[4][4];
    #pragma unroll
    for (int mt = 0; mt < 4; ++mt)
        #pragma unroll
        for (int k = 0; k < 4; ++k)
            acc[mt][k] = (f32x4){0.f, 0.f, 0.f, 0.f};

    const int lm = l & 15;
    const int g  = l >> 4;
    const u16* bbase = Bpack + ((size_t)SBASE * 8 + nth * 4) * 512 + l * 8;
    const u16* abase = lds + (size_t)p * DOCSZ;

    #pragma unroll 2
    for (int s = 0; s < NSL; ++s) {
        const int j  = s >> 2;
        const int e0 = (s & 3) * 32;

        bf16x8 b[4];
        #pragma unroll
        for (int k = 0; k < 4; ++k)
            b[k] = *(const bf16x8*)(bbase + s * 4096 + k * 512);

        const u16* arow = abase + (lm + j) * DSTRIDE + e0 + g * 8;
        bf16x8 a[4];
        #pragma unroll
        for (int mt = 0; mt < 4; ++mt)
            a[mt] = *(const bf16x8*)(arow + mt * (16 * DSTRIDE));

        #pragma unroll
        for (int mt = 0; mt < 4; ++mt)
            #pragma unroll
            for (int k = 0; k < 4; ++k)
                acc[mt][k] = __builtin_amdgcn_mfma_f32_16x16x32_bf16(a[mt], b[k], acc[mt][k], 0, 0, 0);
    }

    #pragma unroll
    for (int k = 0; k < 4; ++k) {
        const int c = nth * 64 + k * 16 + lm;
        const float bias = bk[c];
        float mx = 0.0f;                     // relu output >= 0
        #pragma unroll
        for (int mt = 0; mt < 4; ++mt) {
            #pragma unroll
            for (int r = 0; r < 4; ++r) {
                const int pos = 16 * mt + g * 4 + r;
                const float y = fmaxf(acc[mt][k][r] + bias, 0.0f);
                if (pos < NP) mx = fmaxf(mx, y);
            }
        }
        mx = fmaxf(mx, __shfl_xor(mx, 16));
        mx = fmaxf(mx, __shfl_xor(mx, 32));
        mxout[k] = mx;
    }
}

__global__ __launch_bounds__(512, 4)
void news_kernel(const int* __restrict__ news_words,
                 const u16* __restrict__ we16,
                 const u16* __restrict__ Bpack,
                 const float* __restrict__ b3,
                 const float* __restrict__ b4,
                 const float* __restrict__ b5,
                 const float* __restrict__ fcw, const float* __restrict__ fcb,
                 float* __restrict__ out)
{
    const int n0 = blockIdx.x * 4;
    const int t = threadIdx.x;
    const int w = t >> 6, l = t & 63;
    const int p = w >> 1, nth = w & 1;

    __shared__ u16 lds[4 * DOCSZ];           // 73,984 B; feats alias after convs
    __shared__ int rows[4 * LL];

    if (t < 4 * LL) rows[t] = news_words[(size_t)n0 * LL + t];
    __syncthreads();

    {
        const uint4* weU = (const uint4*)we16;     // 16 uint4 per doc row
        uint4* ldsU = (uint4*)lds;                 // doc stride 1156 uint4
        for (int idx = t; idx < 4096; idx += 512) {
            const int d = idx >> 10, rem = idx & 1023;
            const int row = rem >> 4, c4 = rem & 15;
            ldsU[d * 1156 + row * 17 + c4] = weU[(size_t)rows[d * 64 + row] * 16 + c4];
        }
        if (t < 256) {                             // 4 docs x 4 pad rows x 16
            const int d = t >> 6, rem = t & 63;
            const int row = 64 + (rem >> 4), c4 = rem & 15;
            ldsU[d * 1156 + row * 17 + c4] = (uint4){0u, 0u, 0u, 0u};
        }
    }
    __syncthreads();

    float m3[4], m4[4], m5[4];
    conv_g2<12,  0, 62>(lds, Bpack, b3, p, nth, l, m3);
    conv_g2<16, 12, 61>(lds, Bpack, b4, p, nth, l, m4);
    conv_g2<20, 28, 60>(lds, Bpack, b5, p, nth, l, m5);
    __syncthreads();                          // docs dead beyond this point

    float* feats = (float*)lds;               // [4][384] aliases doc buffer
    if ((l >> 4) == 0) {
        const int lm = l & 15;
        #pragma unroll
        for (int k = 0; k < 4; ++k) {
            const int c = nth * 64 + k * 16 + lm;
            feats[p * 384 +   0 + c] = m3[k];
            feats[p * 384 + 128 + c] = m4[k];
            feats[p * 384 + 256 + c] = m5[k];
        }
    }
    __syncthreads();

    if (t < 128) {
        const float4* wr4 = (const float4*)(fcw + (size_t)t * (3 * CC));
        float a0 = fcb[t], a1 = a0, a2 = a0, a3 = a0;
        for (int f4 = 0; f4 < 96; ++f4) {
            const float4 wv = wr4[f4];
            const float4 x0 = *(const float4*)&feats[0 * 384 + f4 * 4];
            const float4 x1 = *(const float4*)&feats[1 * 384 + f4 * 4];
            const float4 x2 = *(const float4*)&feats[2 * 384 + f4 * 4];
            const float4 x3 = *(const float4*)&feats[3 * 384 + f4 * 4];
            a0 += x0.x * wv.x + x0.y * wv.y + x0.z * wv.z + x0.w * wv.w;
            a1 += x1.x * wv.x + x1.y * wv.y + x1.z * wv.z + x1.w * wv.w;
            a2 += x2.x * wv.x + x2.y * wv.y + x2.z * wv.z + x2.w * wv.w;
            a3 += x3.x * wv.x + x3.y * wv.y + x3.z * wv.z + x3.w * wv.w;
        }
        out[(size_t)(n0 + 0) * EE + t] = a0;
        out[(size_t)(n0 + 1) * EE + t] = a1;
        out[(size_t)(n0 + 2) * EE + t] = a2;
        out[(size_t)(n0 + 3) * EE + t] = a3;
    }
}

// ---------------------------------------------------------------------------
extern "C" void kernel_launch(void* const* d_in, const int* in_sizes, int n_in,
                              void* d_out, int out_size, void* d_ws, size_t ws_size,
                              hipStream_t stream)
{
    const int*   word2news     = (const int*)d_in[0];
    const int*   word2news_len = (const int*)d_in[1];
    const int*   news_words    = (const int*)d_in[2];
    const float* table         = (const float*)d_in[3];
    const float* in_w          = (const float*)d_in[4];
    const float* in_b          = (const float*)d_in[5];
    const float* out_w         = (const float*)d_in[6];
    const float* out_b         = (const float*)d_in[7];
    const float* w3            = (const float*)d_in[8];
    const float* b3            = (const float*)d_in[9];
    const float* w4            = (const float*)d_in[10];
    const float* b4            = (const float*)d_in[11];
    const float* w5            = (const float*)d_in[12];
    const float* b5            = (const float*)d_in[13];
    const float* fcw           = (const float*)d_in[14];
    const float* fcb           = (const float*)d_in[15];

    float* out = (float*)d_out;
    u16* base  = (u16*)d_ws;
    u16* we16  = base;                                   // 2,560,000 u16 (5.12 MB)
    u16* Bpack = base + 2560000;                         //   196,608 u16
    u16* Kn16  = base + 2756608;                         // 1,048,576 u16
    u16* Wn16  = base + 3805184;                         // 1,048,576 u16 (Vn slot)
    u16* Qn16  = base + 4853760;                         // 1,048,576 u16 (11.80 MB)
    const size_t need_qn = (size_t)(4853760 + 1048576) * 2;

    pack_weights<<<48, 256, 0, stream>>>(w3, w4, w5, Bpack);

    if (ws_size >= need_qn) {
        kvqw_proj_kernel<<<NN / 8, 384, 0, stream>>>(table, in_w, in_b,
                                                     out_w, out_b,
                                                     Qn16, Kn16, Wn16);
        word_attn_wn<<<V_WORDS / WPW, 256, 0, stream>>>(
            word2news, word2news_len, Qn16, Kn16, Wn16, we16);
    } else {
        kv_proj_kernel<<<NN / 8, 256, 0, stream>>>(table, in_w, in_b, Kn16, Wn16);
        word_attn_kernel<<<V_WORDS / WPB, 256, 0, stream>>>(
            word2news, word2news_len, table, in_w, in_b, out_w, out_b,
            Kn16, Wn16, we16);
    }

    news_kernel<<<NN / 4, 512, 0, stream>>>(
        news_words, we16, Bpack, b3, b4, b5, fcw, fcb, out);
}

// Round 7
// 370.969 us; speedup vs baseline: 1.0138x; 1.0055x over previous
//
#include <hip/hip_runtime.h>
#include <math.h>

#define V_WORDS 20000
#define MM 32
#define EE 128
#define HH 4
#define DHH 32
#define NN 8192
#define LL 64
#define CC 128

typedef short bf16x8 __attribute__((ext_vector_type(8)));
typedef float f32x4 __attribute__((ext_vector_type(4)));
typedef unsigned short u16;
typedef unsigned int u32;

__device__ __forceinline__ u16 f2bf(float x) {
    u32 u = __float_as_uint(x);
    u32 r = (u + 0x7FFFu + ((u >> 16) & 1u)) >> 16;
    return (u16)r;
}
__device__ __forceinline__ float bflo(u32 u) { return __uint_as_float(u << 16); }
__device__ __forceinline__ float bfhi(u32 u) { return __uint_as_float(u & 0xFFFF0000u); }

// bf16 pair dot-product: 1 VALU op on gfx950 (v_dot2_f32_bf16) vs 6 for the
// unpack+fma fallback. Guarded: falls back to exact-equivalent f32 math.
#if defined(__has_builtin)
#  if __has_builtin(__builtin_amdgcn_fdot2_f32_bf16)
#    define USE_BF16_DOT2 1
#  endif
#endif
#ifdef USE_BF16_DOT2
typedef __bf16 v2bf __attribute__((ext_vector_type(2)));
#endif

__device__ __forceinline__ float dot2bf(u32 a, u32 b, float c) {
#ifdef USE_BF16_DOT2
    return __builtin_amdgcn_fdot2_f32_bf16(
        __builtin_bit_cast(v2bf, a), __builtin_bit_cast(v2bf, b), c, false);
#else
    return c + bflo(a) * bflo(b) + bfhi(a) * bfhi(b);
#endif
}

// ---------------------------------------------------------------------------
// Kernel 0: pack conv weights into bf16 MFMA B-fragment order (unchanged).
// ---------------------------------------------------------------------------
__global__ __launch_bounds__(256)
void pack_weights(const float* __restrict__ w3,
                  const float* __restrict__ w4,
                  const float* __restrict__ w5,
                  u16* __restrict__ Bpack)
{
    const int s = blockIdx.x;
    const int t = threadIdx.x;
    const int lane = t & 63;

    const float* src;
    int K, sl;
    if (s < 12)      { src = w3; K = 3; sl = s; }
    else if (s < 28) { src = w4; K = 4; sl = s - 12; }
    else             { src = w5; K = 5; sl = s - 28; }
    const int j  = sl >> 2;
    const int e0 = (sl & 3) * 32;

    for (int nt = (t >> 6); nt < 8; nt += 4) {
        const int c = nt * 16 + (lane & 15);
        const int kb = (lane >> 4) * 8;
        u16 vals[8];
        #pragma unroll
        for (int i = 0; i < 8; ++i) {
            const int e = e0 + kb + i;
            vals[i] = f2bf(src[(c * EE + e) * K + j]);
        }
        u16* dst = Bpack + (((size_t)s * 8 + nt) * 64 + lane) * 8;
        *(bf16x8*)dst = *(const bf16x8*)vals;
    }
}

// ---------------------------------------------------------------------------
// Kernel A (fallback, ws too small): Kn/Vn projections (R15 path).
// ---------------------------------------------------------------------------
__global__ __launch_bounds__(256)
void kv_proj_kernel(const float* __restrict__ table,
                    const float* __restrict__ in_w,
                    const float* __restrict__ in_b,
                    u16* __restrict__ Kn16, u16* __restrict__ Vn16)
{
    const int n0 = blockIdx.x * 8;
    const int t = threadIdx.x;
    __shared__ float tbl[8][EE];
    {
        const int r = t >> 5, q4 = (t & 31) * 4;
        *(float4*)&tbl[r][q4] = *(const float4*)&table[(size_t)(n0 + r) * EE + q4];
    }
    __syncthreads();

    const int sel = t >> 7;
    const int i = t & 127;
    const float* w = in_w + (size_t)(sel + 1) * EE * EE + (size_t)i * EE;
    const float bias = in_b[(sel + 1) * EE + i];

    float acc[8];
    #pragma unroll
    for (int r = 0; r < 8; ++r) acc[r] = bias;
    for (int k = 0; k < EE; k += 4) {
        const float4 wv = *(const float4*)&w[k];
        #pragma unroll
        for (int r = 0; r < 8; ++r) {
            acc[r] += tbl[r][k]     * wv.x + tbl[r][k + 1] * wv.y
                    + tbl[r][k + 2] * wv.z + tbl[r][k + 3] * wv.w;
        }
    }
    u16* dst = sel ? Vn16 : Kn16;
    #pragma unroll
    for (int r = 0; r < 8; ++r) dst[(size_t)(n0 + r) * EE + i] = f2bf(acc[r]);
}

// ---------------------------------------------------------------------------
// Kernel A'' (R19 form, R22-proven): Q/K/W projections over 8192 news rows.
// ---------------------------------------------------------------------------
__global__ __launch_bounds__(384)
void kvqw_proj_kernel(const float* __restrict__ table,
                      const float* __restrict__ in_w,
                      const float* __restrict__ in_b,
                      const float* __restrict__ out_w,
                      const float* __restrict__ out_b,
                      u16* __restrict__ Qn16,
                      u16* __restrict__ Kn16,
                      u16* __restrict__ Wn16)
{
    const int n0 = blockIdx.x * 8;
    const int t = threadIdx.x;
    __shared__ float tbl[8][EE];
    __shared__ float vsh[8][EE];
    if (t < 256) {
        const int r = t >> 5, q4 = (t & 31) * 4;
        *(float4*)&tbl[r][q4] = *(const float4*)&table[(size_t)(n0 + r) * EE + q4];
    }
    __syncthreads();

    const int sel = t >> 7;                 // 0 = Q, 1 = K, 2 = V
    const int i = t & 127;
    const float* w = in_w + (size_t)sel * EE * EE + (size_t)i * EE;
    const float bias = in_b[sel * EE + i];

    float acc[8];
    #pragma unroll
    for (int r = 0; r < 8; ++r) acc[r] = bias;
    for (int k = 0; k < EE; k += 4) {
        const float4 wv = *(const float4*)&w[k];
        #pragma unroll
        for (int r = 0; r < 8; ++r) {
            acc[r] += tbl[r][k]     * wv.x + tbl[r][k + 1] * wv.y
                    + tbl[r][k + 2] * wv.z + tbl[r][k + 3] * wv.w;
        }
    }
    if (sel == 0) {
        #pragma unroll
        for (int r = 0; r < 8; ++r) Qn16[(size_t)(n0 + r) * EE + i] = f2bf(acc[r]);
    } else if (sel == 1) {
        #pragma unroll
        for (int r = 0; r < 8; ++r) Kn16[(size_t)(n0 + r) * EE + i] = f2bf(acc[r]);
    } else {
        #pragma unroll
        for (int r = 0; r < 8; ++r) vsh[r][i] = acc[r];   // keep V fp32 for phase 2
    }
    __syncthreads();

    // Phase 2: Wn[r][i] = vsh[r] . out_w[i] + out_b[i]
    {
        const int g = t >> 7;
        const int r0 = g, r1 = g + 3, r2 = g + 6;       // r2 == 8 invalid for g==2
        const int r2c = (r2 < 8) ? r2 : 7;
        const float* wr = out_w + (size_t)i * EE;
        const float ob = out_b[i];
        float a0 = ob, a1 = ob, a2 = ob;
        #pragma unroll 4
        for (int k = 0; k < EE; k += 4) {
            const float4 wv = *(const float4*)&wr[k];
            a0 += vsh[r0][k]   * wv.x + vsh[r0][k+1] * wv.y
                + vsh[r0][k+2] * wv.z + vsh[r0][k+3] * wv.w;
            a1 += vsh[r1][k]   * wv.x + vsh[r1][k+1] * wv.y
                + vsh[r1][k+2] * wv.z + vsh[r1][k+3] * wv.w;
            a2 += vsh[r2c][k]   * wv.x + vsh[r2c][k+1] * wv.y
                + vsh[r2c][k+2] * wv.z + vsh[r2c][k+3] * wv.w;
        }
        Wn16[(size_t)(n0 + r0) * EE + i] = f2bf(a0);
        Wn16[(size_t)(n0 + r1) * EE + i] = f2bf(a1);
        if (r2 < 8) Wn16[(size_t)(n0 + r2) * EE + i] = f2bf(a2);
    }
}

// ---------------------------------------------------------------------------
// Kernel B (fallback): per-word attention, R15 path (unchanged).
// ---------------------------------------------------------------------------
#define WPB 8
__global__ __launch_bounds__(256, 3)
void word_attn_kernel(const int* __restrict__ word2news,
                      const int* __restrict__ word2news_len,
                      const float* __restrict__ table,
                      const float* __restrict__ in_w,
                      const float* __restrict__ in_b,
                      const float* __restrict__ out_w,
                      const float* __restrict__ out_b,
                      const u16* __restrict__ Kn16,
                      const u16* __restrict__ Vn16,
                      u16* __restrict__ we16)
{
    const int v0 = blockIdx.x * WPB;
    const int t = threadIdx.x;

    __shared__ int   rows[WPB][MM];
    __shared__ int   lenS[WPB];
    __shared__ float q[WPB][EE];
    __shared__ float qh[WPB][EE];
    __shared__ float attn[WPB][HH][MM];
    __shared__ float osh[WPB][EE];

    {
        const int w = t >> 5, m = t & 31;
        rows[w][m] = word2news[(size_t)(v0 + w) * MM + m];
        if (t < WPB) lenS[t] = word2news_len[v0 + t];
    }
    __syncthreads();

    {
        const int w = t >> 5, d0 = (t & 31) * 4;
        const int L = lenS[w];
        float4 a = {0.f, 0.f, 0.f, 0.f};
        #pragma unroll 4
        for (int m = 0; m < MM; ++m) {
            const float4 x = *(const float4*)&table[(size_t)rows[w][m] * EE + d0];
            if (m < L) { a.x += x.x; a.y += x.y; a.z += x.z; a.w += x.w; }
        }
        const float inv = (L > 0) ? 1.0f / (float)L : 0.0f;
        a.x *= inv; a.y *= inv; a.z *= inv; a.w *= inv;
        *(float4*)&q[w][d0] = a;
    }
    __syncthreads();

    {
        const int g = t >> 7, i = t & 127;
        const float* wr = in_w + (size_t)i * EE;
        float acc[4] = {0.f, 0.f, 0.f, 0.f};
        #pragma unroll 4
        for (int k = 0; k < EE; k += 4) {
            const float4 wv = *(const float4*)&wr[k];
            #pragma unroll
            for (int w4 = 0; w4 < 4; ++w4) {
                const float* qw = q[g * 4 + w4];
                acc[w4] += qw[k] * wv.x + qw[k + 1] * wv.y
                         + qw[k + 2] * wv.z + qw[k + 3] * wv.w;
            }
        }
        const float b = in_b[i];
        #pragma unroll
        for (int w4 = 0; w4 < 4; ++w4) qh[g * 4 + w4][i] = acc[w4] + b;
    }
    __syncthreads();

    {
        const int w = t >> 5, m = t & 31;
        const int L = lenS[w];
        float s[HH] = {-1e9f, -1e9f, -1e9f, -1e9f};
        if (m < L) {
            const uint4* kr = (const uint4*)(Kn16 + (size_t)rows[w][m] * EE);
            #pragma unroll 1
            for (int h = 0; h < HH; ++h) {
                float a = 0.f;
                #pragma unroll
                for (int k8 = 0; k8 < 4; ++k8) {
                    const uint4 u = kr[h * 4 + k8];
                    const float4 q0 = *(const float4*)&qh[w][h * 32 + k8 * 8];
                    const float4 q1 = *(const float4*)&qh[w][h * 32 + k8 * 8 + 4];
                    a += q0.x * bflo(u.x) + q0.y * bfhi(u.x)
                       + q0.z * bflo(u.y) + q0.w * bfhi(u.y)
                       + q1.x * bflo(u.z) + q1.y * bfhi(u.z)
                       + q1.z * bflo(u.w) + q1.w * bfhi(u.w);
                }
                s[h] = a * 0.17677669529663687f;
            }
        }
        #pragma unroll
        for (int h = 0; h < HH; ++h) {
            float mx = s[h];
            #pragma unroll
            for (int off = 16; off > 0; off >>= 1)
                mx = fmaxf(mx, __shfl_xor(mx, off, 32));
            const float ex = expf(s[h] - mx);
            float sum = ex;
            #pragma unroll
            for (int off = 16; off > 0; off >>= 1)
                sum += __shfl_xor(sum, off, 32);
            attn[w][h][m] = ex / sum;
        }
    }
    __syncthreads();

    {
        const int w = t >> 5, d0 = (t & 31) * 4;
        const int h = d0 >> 5;
        float4 a = {0.f, 0.f, 0.f, 0.f};
        #pragma unroll 4
        for (int m = 0; m < MM; ++m) {
            const float aw = attn[w][h][m];
            const u32* vr = (const u32*)(Vn16 + (size_t)rows[w][m] * EE + d0);
            const u32 u0 = vr[0], u1 = vr[1];
            a.x += aw * bflo(u0); a.y += aw * bfhi(u0);
            a.z += aw * bflo(u1); a.w += aw * bfhi(u1);
        }
        *(float4*)&osh[w][d0] = a;
    }
    __syncthreads();

    {
        const int g = t >> 7, i = t & 127;
        const float* wr = out_w + (size_t)i * EE;
        float acc[4] = {0.f, 0.f, 0.f, 0.f};
        #pragma unroll 4
        for (int k = 0; k < EE; k += 4) {
            const float4 wv = *(const float4*)&wr[k];
            #pragma unroll
            for (int w4 = 0; w4 < 4; ++w4) {
                const float* ow = osh[g * 4 + w4];
                acc[w4] += ow[k] * wv.x + ow[k + 1] * wv.y
                         + ow[k + 2] * wv.z + ow[k + 3] * wv.w;
            }
        }
        const float b = out_b[i];
        #pragma unroll
        for (int w4 = 0; w4 < 4; ++w4) {
            const int w = g * 4 + w4;
            we16[(size_t)(v0 + w) * EE + i] =
                (lenS[w] > 0) ? f2bf(acc[w4] + b) : (u16)0;
        }
    }
}

// ---------------------------------------------------------------------------
// Kernel B'' (R26 = R22 MEASURED BEST + __expf): per-word attention, fully
// fused. R22 structure restored exactly — 8 words/block, 32 lanes/word,
// 3 barriers (phase-aligned gathers keep each phase's working set = one
// 2MB array = per-XCD-L2-resident), dynamic L loops, packed bf16 qh,
// dot2bf score. Envelope mapped and closed by R23/R24/R25 (all regressed):
//   - barrier-free + sched_barrier: +11.6us (phase mixing, 6MB working set)
//   - K-row register prefetch: +9.8us (vmcnt counts oldest-first: the
//     Q-loop's first wait drains all 16 K loads -> serializes, +64 VGPR)
//   - 64-lane wave per word, halved chains: +8.5us (overhead > latency win)
// Only surviving delta vs R22: expf -> __expf (fewer VALU, absmax-proven
// identical across R23-R25).
// ---------------------------------------------------------------------------
__global__ __launch_bounds__(256, 3)
void word_attn_wn(const int* __restrict__ word2news,
                  const int* __restrict__ word2news_len,
                  const u16* __restrict__ Qn16,
                  const u16* __restrict__ Kn16,
                  const u16* __restrict__ Wn16,
                  u16* __restrict__ we16)
{
    const int v0 = blockIdx.x * WPB;
    const int t = threadIdx.x;

    __shared__ int   rows[WPB][MM];
    __shared__ int   lenS[WPB];
    __shared__ __align__(16) u32 qhp[WPB][EE / 2];   // bf16-pair packed query
    __shared__ float attn[WPB][HH][MM];

    {
        const int w = t >> 5, m = t & 31;
        rows[w][m] = word2news[(size_t)(v0 + w) * MM + m];
        if (t < WPB) lenS[t] = word2news_len[v0 + t];
    }
    __syncthreads();

    // qh = mean of gathered Qn rows (bias included; exact — weights sum to 1).
    // Loop to L only (uniform per 32-lane group); pack result as bf16 pairs.
    {
        const int w = t >> 5, d0 = (t & 31) * 4;
        const int L = lenS[w];
        float4 a = {0.f, 0.f, 0.f, 0.f};
        #pragma unroll 4
        for (int mm = 0; mm < L; ++mm) {
            const uint2 u = *(const uint2*)(Qn16 + (size_t)rows[w][mm] * EE + d0);
            a.x += bflo(u.x); a.y += bfhi(u.x);
            a.z += bflo(u.y); a.w += bfhi(u.y);
        }
        const float inv = (L > 0) ? 1.0f / (float)L : 0.0f;
        a.x *= inv; a.y *= inv; a.z *= inv; a.w *= inv;
        qhp[w][(d0 >> 1) + 0] = (u32)f2bf(a.x) | ((u32)f2bf(a.y) << 16);
        qhp[w][(d0 >> 1) + 1] = (u32)f2bf(a.z) | ((u32)f2bf(a.w) << 16);
    }
    __syncthreads();

    // scores (gather Kn rows) + softmax over m; head-PAIR at a time with the
    // pair's 8 uint4 (128B) prefetched before any dot -> 8 loads in flight.
    {
        const int w = t >> 5, m = t & 31;
        const int L = lenS[w];
        float s[HH] = {-1e9f, -1e9f, -1e9f, -1e9f};
        if (m < L) {
            const uint4* kr = (const uint4*)(Kn16 + (size_t)rows[w][m] * EE);
            const u32* qp = qhp[w];
            #pragma unroll
            for (int hp = 0; hp < 2; ++hp) {
                uint4 kq[8];
                #pragma unroll
                for (int q8 = 0; q8 < 8; ++q8) kq[q8] = kr[hp * 8 + q8];
                #pragma unroll
                for (int hl = 0; hl < 2; ++hl) {
                    const int h = hp * 2 + hl;
                    float a = 0.f;
                    #pragma unroll
                    for (int k8 = 0; k8 < 4; ++k8) {
                        const uint4 u  = kq[hl * 4 + k8];
                        const uint4 qq = *(const uint4*)&qp[h * 16 + k8 * 4];
                        a = dot2bf(u.x, qq.x, a);
                        a = dot2bf(u.y, qq.y, a);
                        a = dot2bf(u.z, qq.z, a);
                        a = dot2bf(u.w, qq.w, a);
                    }
                    s[h] = a * 0.17677669529663687f;
                }
            }
        }
        #pragma unroll
        for (int h = 0; h < HH; ++h) {
            float mx = s[h];
            #pragma unroll
            for (int off = 16; off > 0; off >>= 1)
                mx = fmaxf(mx, __shfl_xor(mx, off, 32));
            const float ex = __expf(s[h] - mx);    // masked lanes underflow to 0
            float sum = ex;
            #pragma unroll
            for (int off = 16; off > 0; off >>= 1)
                sum += __shfl_xor(sum, off, 32);
            attn[w][h][m] = ex / sum;
        }
    }
    __syncthreads();

    // we = sum_{m<L} attn_m * Wn[rows[m]]  (out-proj + bias pre-folded into
    // Wn; attn==0 exactly for m>=L so the truncation is exact).
    {
        const int w = t >> 5, d0 = (t & 31) * 4;
        const int h = d0 >> 5;
        const int L = lenS[w];
        float4 a = {0.f, 0.f, 0.f, 0.f};
        #pragma unroll 4
        for (int mm = 0; mm < L; ++mm) {
            const float aw = attn[w][h][mm];
            const uint2 u = *(const uint2*)(Wn16 + (size_t)rows[w][mm] * EE + d0);
            a.x += aw * bflo(u.x); a.y += aw * bfhi(u.x);
            a.z += aw * bflo(u.y); a.w += aw * bfhi(u.y);
        }
        u32 lo = 0u, hi = 0u;
        if (L > 0) {
            lo = (u32)f2bf(a.x) | ((u32)f2bf(a.y) << 16);
            hi = (u32)f2bf(a.z) | ((u32)f2bf(a.w) << 16);
        }
        u32* dst = (u32*)(we16 + (size_t)(v0 + w) * EE + d0);
        dst[0] = lo; dst[1] = hi;
    }
}

// ---------------------------------------------------------------------------
// Kernel 2: implicit-GEMM conv — R16/R18 MEASURED OPTIMUM, unchanged.
// (#pragma unroll 2; full unroll spills — R20 measured 14x regression.)
// ---------------------------------------------------------------------------
#define DSTRIDE 136              // u16 per doc row (16B-aligned, 68 words)
#define DOCSZ   (68 * DSTRIDE)   // u16 per doc (64 data rows + 4 zero rows)

template<int NSL, int SBASE, int NP>
__device__ __forceinline__ void conv_g2(const u16* __restrict__ lds,
                                        const u16* __restrict__ Bpack,
                                        const float* __restrict__ bk,
                                        int p, int nth, int l,
                                        float (&mxout)[4])
{
    f32x4 acc[4][4];
    #pragma unroll
    for (int mt = 0; mt < 4; ++mt)
        #pragma unroll
        for (int k = 0; k < 4; ++k)
            acc[mt][k] = (f32x4){0.f, 0.f, 0.f, 0.f};

    const int lm = l & 15;
    const int g  = l >> 4;
    const u16* bbase = Bpack + ((size_t)SBASE * 8 + nth * 4) * 512 + l * 8;
    const u16* abase = lds + (size_t)p * DOCSZ;

    #pragma unroll 2
    for (int s = 0; s < NSL; ++s) {
        const int j  = s >> 2;
        const int e0 = (s & 3) * 32;

        bf16x8 b[4];
        #pragma unroll
        for (int k = 0; k < 4; ++k)
            b[k] = *(const bf16x8*)(bbase + s * 4096 + k * 512);

        const u16* arow = abase + (lm + j) * DSTRIDE + e0 + g * 8;
        bf16x8 a[4];
        #pragma unroll
        for (int mt = 0; mt < 4; ++mt)
            a[mt] = *(const bf16x8*)(arow + mt * (16 * DSTRIDE));

        #pragma unroll
        for (int mt = 0; mt < 4; ++mt)
            #pragma unroll
            for (int k = 0; k < 4; ++k)
                acc[mt][k] = __builtin_amdgcn_mfma_f32_16x16x32_bf16(a[mt], b[k], acc[mt][k], 0, 0, 0);
    }

    #pragma unroll
    for (int k = 0; k < 4; ++k) {
        const int c = nth * 64 + k * 16 + lm;
        const float bias = bk[c];
        float mx = 0.0f;                     // relu output >= 0
        #pragma unroll
        for (int mt = 0; mt < 4; ++mt) {
            #pragma unroll
            for (int r = 0; r < 4; ++r) {
                const int pos = 16 * mt + g * 4 + r;
                const float y = fmaxf(acc[mt][k][r] + bias, 0.0f);
                if (pos < NP) mx = fmaxf(mx, y);
            }
        }
        mx = fmaxf(mx, __shfl_xor(mx, 16));
        mx = fmaxf(mx, __shfl_xor(mx, 32));
        mxout[k] = mx;
    }
}

__global__ __launch_bounds__(512, 4)
void news_kernel(const int* __restrict__ news_words,
                 const u16* __restrict__ we16,
                 const u16* __restrict__ Bpack,
                 const float* __restrict__ b3,
                 const float* __restrict__ b4,
                 const float* __restrict__ b5,
                 const float* __restrict__ fcw, const float* __restrict__ fcb,
                 float* __restrict__ out)
{
    const int n0 = blockIdx.x * 4;
    const int t = threadIdx.x;
    const int w = t >> 6, l = t & 63;
    const int p = w >> 1, nth = w & 1;

    __shared__ u16 lds[4 * DOCSZ];           // 73,984 B; feats alias after convs
    __shared__ int rows[4 * LL];

    if (t < 4 * LL) rows[t] = news_words[(size_t)n0 * LL + t];
    __syncthreads();

    {
        const uint4* weU = (const uint4*)we16;     // 16 uint4 per doc row
        uint4* ldsU = (uint4*)lds;                 // doc stride 1156 uint4
        for (int idx = t; idx < 4096; idx += 512) {
            const int d = idx >> 10, rem = idx & 1023;
            const int row = rem >> 4, c4 = rem & 15;
            ldsU[d * 1156 + row * 17 + c4] = weU[(size_t)rows[d * 64 + row] * 16 + c4];
        }
        if (t < 256) {                             // 4 docs x 4 pad rows x 16
            const int d = t >> 6, rem = t & 63;
            const int row = 64 + (rem >> 4), c4 = rem & 15;
            ldsU[d * 1156 + row * 17 + c4] = (uint4){0u, 0u, 0u, 0u};
        }
    }
    __syncthreads();

    float m3[4], m4[4], m5[4];
    conv_g2<12,  0, 62>(lds, Bpack, b3, p, nth, l, m3);
    conv_g2<16, 12, 61>(lds, Bpack, b4, p, nth, l, m4);
    conv_g2<20, 28, 60>(lds, Bpack, b5, p, nth, l, m5);
    __syncthreads();                          // docs dead beyond this point

    float* feats = (float*)lds;               // [4][384] aliases doc buffer
    if ((l >> 4) == 0) {
        const int lm = l & 15;
        #pragma unroll
        for (int k = 0; k < 4; ++k) {
            const int c = nth * 64 + k * 16 + lm;
            feats[p * 384 +   0 + c] = m3[k];
            feats[p * 384 + 128 + c] = m4[k];
            feats[p * 384 + 256 + c] = m5[k];
        }
    }
    __syncthreads();

    if (t < 128) {
        const float4* wr4 = (const float4*)(fcw + (size_t)t * (3 * CC));
        float a0 = fcb[t], a1 = a0, a2 = a0, a3 = a0;
        for (int f4 = 0; f4 < 96; ++f4) {
            const float4 wv = wr4[f4];
            const float4 x0 = *(const float4*)&feats[0 * 384 + f4 * 4];
            const float4 x1 = *(const float4*)&feats[1 * 384 + f4 * 4];
            const float4 x2 = *(const float4*)&feats[2 * 384 + f4 * 4];
            const float4 x3 = *(const float4*)&feats[3 * 384 + f4 * 4];
            a0 += x0.x * wv.x + x0.y * wv.y + x0.z * wv.z + x0.w * wv.w;
            a1 += x1.x * wv.x + x1.y * wv.y + x1.z * wv.z + x1.w * wv.w;
            a2 += x2.x * wv.x + x2.y * wv.y + x2.z * wv.z + x2.w * wv.w;
            a3 += x3.x * wv.x + x3.y * wv.y + x3.z * wv.z + x3.w * wv.w;
        }
        out[(size_t)(n0 + 0) * EE + t] = a0;
        out[(size_t)(n0 + 1) * EE + t] = a1;
        out[(size_t)(n0 + 2) * EE + t] = a2;
        out[(size_t)(n0 + 3) * EE + t] = a3;
    }
}

// ---------------------------------------------------------------------------
extern "C" void kernel_launch(void* const* d_in, const int* in_sizes, int n_in,
                              void* d_out, int out_size, void* d_ws, size_t ws_size,
                              hipStream_t stream)
{
    const int*   word2news     = (const int*)d_in[0];
    const int*   word2news_len = (const int*)d_in[1];
    const int*   news_words    = (const int*)d_in[2];
    const float* table         = (const float*)d_in[3];
    const float* in_w          = (const float*)d_in[4];
    const float* in_b          = (const float*)d_in[5];
    const float* out_w         = (const float*)d_in[6];
    const float* out_b         = (const float*)d_in[7];
    const float* w3            = (const float*)d_in[8];
    const float* b3            = (const float*)d_in[9];
    const float* w4            = (const float*)d_in[10];
    const float* b4            = (const float*)d_in[11];
    const float* w5            = (const float*)d_in[12];
    const float* b5            = (const float*)d_in[13];
    const float* fcw           = (const float*)d_in[14];
    const float* fcb           = (const float*)d_in[15];

    float* out = (float*)d_out;
    u16* base  = (u16*)d_ws;
    u16* we16  = base;                                   // 2,560,000 u16 (5.12 MB)
    u16* Bpack = base + 2560000;                         //   196,608 u16
    u16* Kn16  = base + 2756608;                         // 1,048,576 u16
    u16* Wn16  = base + 3805184;                         // 1,048,576 u16 (Vn slot)
    u16* Qn16  = base + 4853760;                         // 1,048,576 u16 (11.80 MB)
    const size_t need_qn = (size_t)(4853760 + 1048576) * 2;

    pack_weights<<<48, 256, 0, stream>>>(w3, w4, w5, Bpack);

    if (ws_size >= need_qn) {
        kvqw_proj_kernel<<<NN / 8, 384, 0, stream>>>(table, in_w, in_b,
                                                     out_w, out_b,
                                                     Qn16, Kn16, Wn16);
        word_attn_wn<<<V_WORDS / WPB, 256, 0, stream>>>(
            word2news, word2news_len, Qn16, Kn16, Wn16, we16);
    } else {
        kv_proj_kernel<<<NN / 8, 256, 0, stream>>>(table, in_w, in_b, Kn16, Wn16);
        word_attn_kernel<<<V_WORDS / WPB, 256, 0, stream>>>(
            word2news, word2news_len, table, in_w, in_b, out_w, out_b,
            Kn16, Wn16, we16);
    }

    news_kernel<<<NN / 4, 512, 0, stream>>>(
        news_words, we16, Bpack, b3, b4, b5, fcw, fcb, out);
}